// Round 9
// baseline (422.745 us; speedup 1.0000x reference)
//
#include <hip/hip_runtime.h>
#include <hip/hip_bf16.h>
#include <math.h>

// ---------------------------------------------------------------------------
// GNN_72103910966081: 4-layer LEConv GNN, N=50000, E=600000, D=128.
// Round 9: dispatch-count reduction — standardize fused into layer-1 GEMM
// staging (kills 38MB round trip), wsum fused into csr_fill (atomics),
// colstats reduced via per-block atomics (kills 1-block serial reduce),
// both weight converts merged. ~20 -> 15 dispatches.
// ---------------------------------------------------------------------------

typedef _Float16 f16x8 __attribute__((ext_vector_type(8)));
typedef _Float16 f16x4 __attribute__((ext_vector_type(4)));
typedef float f32x4 __attribute__((ext_vector_type(4)));

#define LSTRIDE 136   // halves per LDS row: 128 + 8 (16B-aligned, breaks 2^k banks)

__device__ inline float wave_reduce_sum(float v) {
    #pragma unroll
    for (int off = 32; off > 0; off >>= 1)
        v += __shfl_xor(v, off, 64);
    return v;
}

// ===================== CSR build =====================

__global__ __launch_bounds__(256) void hist_kernel(
    const int* __restrict__ dst, int* __restrict__ deg, int E)
{
    int e = blockIdx.x * 256 + threadIdx.x;
    if (e < E) atomicAdd(&deg[dst[e]], 1);
}

__global__ __launch_bounds__(256) void scan_pass1(
    const int* __restrict__ deg, int N, int* __restrict__ partial)
{
    __shared__ int sh[256];
    int t = threadIdx.x;
    int base = blockIdx.x * 1024 + t * 4;
    int s = 0;
    #pragma unroll
    for (int i = 0; i < 4; ++i) { int idx = base + i; if (idx < N) s += deg[idx]; }
    sh[t] = s; __syncthreads();
    for (int off = 128; off > 0; off >>= 1) {
        if (t < off) sh[t] += sh[t + off];
        __syncthreads();
    }
    if (t == 0) partial[blockIdx.x] = sh[0];
}

__global__ __launch_bounds__(256) void scan_pass2(int* __restrict__ partial, int nb)
{
    __shared__ int sh[256];
    int t = threadIdx.x;
    sh[t] = (t < nb) ? partial[t] : 0;
    __syncthreads();
    for (int off = 1; off < 256; off <<= 1) {
        int x = sh[t];
        if (t >= off) x += sh[t - off];
        __syncthreads();
        sh[t] = x;
        __syncthreads();
    }
    if (t < nb) partial[t] = (t > 0) ? sh[t - 1] : 0;   // exclusive
}

__global__ __launch_bounds__(256) void scan_pass3(
    const int* __restrict__ deg, int N, const int* __restrict__ partial,
    int* __restrict__ rowptr, int* __restrict__ fill, int E)
{
    __shared__ int sh[256];
    int t = threadIdx.x;
    int base = blockIdx.x * 1024 + t * 4;
    int v[4]; int s = 0;
    #pragma unroll
    for (int i = 0; i < 4; ++i) { int idx = base + i; v[i] = (idx < N) ? deg[idx] : 0; s += v[i]; }
    sh[t] = s; __syncthreads();
    for (int off = 1; off < 256; off <<= 1) {
        int x = sh[t];
        if (t >= off) x += sh[t - off];
        __syncthreads();
        sh[t] = x;
        __syncthreads();
    }
    int off0 = partial[blockIdx.x] + ((t > 0) ? sh[t - 1] : 0);
    #pragma unroll
    for (int i = 0; i < 4; ++i) {
        int idx = base + i;
        if (idx < N) { rowptr[idx] = off0; fill[idx] = off0; off0 += v[i]; }
    }
    if (blockIdx.x == 0 && t == 0) rowptr[N] = E;
}

// fills CSR AND accumulates wsum (atomics) in one pass
__global__ __launch_bounds__(256) void csr_fill_kernel(
    const int* __restrict__ src, const int* __restrict__ dst,
    const float* __restrict__ ew, int* __restrict__ fill,
    int2* __restrict__ csr, float* __restrict__ wsum, int E)
{
    int e = blockIdx.x * 256 + threadIdx.x;
    if (e >= E) return;
    int d = dst[e];
    float w = ew[e];
    int pos = atomicAdd(&fill[d], 1);
    csr[pos] = make_int2(src[e], __float_as_int(w));
    atomicAdd(&wsum[d], w);
}

// ===================== weight convert+transpose (both sets, one launch) ====
// fp32 [k][n] -> fp16 [n][k] for [W1|W2|W3] of each set.

__global__ __launch_bounds__(256) void convert_weights_kernel(
    const float* __restrict__ W1a, const float* __restrict__ W2a,
    const float* __restrict__ W3a, _Float16* __restrict__ Wta,
    const float* __restrict__ W1b, const float* __restrict__ W2b,
    const float* __restrict__ W3b, _Float16* __restrict__ Wtb)
{
    int idx = blockIdx.x * 256 + threadIdx.x;   // over 2*384*128
    if (idx >= 2 * 384 * 128) return;
    int set = idx >= 384 * 128;
    int id = idx - set * 384 * 128;
    int n = id >> 7, k = id & 127;
    const float* W = set ? ((n < 128) ? W1b : (n < 256) ? W2b : W3b)
                         : ((n < 128) ? W1a : (n < 256) ? W2a : W3a);
    _Float16* Wt = set ? Wtb : Wta;
    int c = n & 127;
    Wt[id] = (_Float16)W[k * 128 + c];
}

// ===================== input standardization stats =====================
// coalesced float4 sweeps; per-block partial -> global atomics (stats[256]).

#define CS_BLOCKS 512

__global__ __launch_bounds__(256) void colstats_kernel(
    const float* __restrict__ x, int N, float* __restrict__ stats)
{
    __shared__ float shs[256][4];
    __shared__ float shq[256][4];
    int t = threadIdx.x;
    int g = t >> 5;
    int c = t & 31;
    const float4* xv = (const float4*)x;    // row stride 32
    float s0=0.f,s1=0.f,s2=0.f,s3=0.f, q0=0.f,q1=0.f,q2=0.f,q3=0.f;
    for (int r = blockIdx.x * 8 + g; r < N; r += CS_BLOCKS * 8) {
        float4 v = xv[(size_t)r * 32 + c];
        s0 += v.x; s1 += v.y; s2 += v.z; s3 += v.w;
        q0 += v.x*v.x; q1 += v.y*v.y; q2 += v.z*v.z; q3 += v.w*v.w;
    }
    shs[t][0]=s0; shs[t][1]=s1; shs[t][2]=s2; shs[t][3]=s3;
    shq[t][0]=q0; shq[t][1]=q1; shq[t][2]=q2; shq[t][3]=q3;
    __syncthreads();
    if (t < 32) {
        float S[4] = {0,0,0,0}, Q[4] = {0,0,0,0};
        #pragma unroll
        for (int gg = 0; gg < 8; ++gg) {
            #pragma unroll
            for (int i = 0; i < 4; ++i) {
                S[i] += shs[t + 32*gg][i];
                Q[i] += shq[t + 32*gg][i];
            }
        }
        #pragma unroll
        for (int i = 0; i < 4; ++i) {
            atomicAdd(&stats[t*4 + i], S[i]);
            atomicAdd(&stats[128 + t*4 + i], Q[i]);
        }
    }
}

__global__ void finalize_stats_kernel(const float* __restrict__ stats, int N,
                                      float* __restrict__ mean,
                                      float* __restrict__ rstd)
{
    int f = threadIdx.x;  // 128 threads
    float s = stats[f], ss = stats[128 + f];
    float m = s / (float)N;
    float var = (ss - s * s / (float)N) / (float)(N - 1);  // ddof=1
    var = fmaxf(var, 0.f);
    mean[f] = m;
    rstd[f] = 1.f / (sqrtf(var) + 1e-6f);
}

// ===================== MFMA fused GEMM (persistent, B in registers) ========
// Variant 1: reads fp16 h (layers 2..3).

__global__ __launch_bounds__(256, 2) void gemm_mfma_kernel(
    const _Float16* __restrict__ h, int N, int nTiles,
    const _Float16* __restrict__ Wt,
    const float* __restrict__ b1,
    const float* __restrict__ b3,
    const float* __restrict__ wsum,
    _Float16* __restrict__ out_a, _Float16* __restrict__ out_d)
{
    __shared__ _Float16 ldsS[64 * LSTRIDE];
    __shared__ _Float16 lds_a[64 * LSTRIDE];
    __shared__ _Float16 lds_d[64 * LSTRIDE];

    int t = threadIdx.x;
    int wave = t >> 6;
    int lane = t & 63;
    int quad = lane >> 4;
    int c16  = lane & 15;

    const f16x8* wv = (const f16x8*)Wt;
    int ntl[6] = {2*wave, 2*wave+1, 8+2*wave, 9+2*wave, 16+2*wave, 17+2*wave};
    f16x8 bfrag[6][4];
    #pragma unroll
    for (int j = 0; j < 6; ++j) {
        int nrow = ntl[j] * 16 + c16;
        #pragma unroll
        for (int s = 0; s < 4; ++s)
            bfrag[j][s] = wv[(size_t)nrow * 16 + s * 4 + quad];
    }
    float bb1[2], bb3[2];
    #pragma unroll
    for (int j = 0; j < 2; ++j) {
        int col = (2*wave + j) * 16 + c16;
        bb1[j] = b1[col];
        bb3[j] = b3[col];
    }

    const f16x8* hv = (const f16x8*)h;
    f16x8* oa = (f16x8*)out_a;
    f16x8* od = (f16x8*)out_d;

    for (int tile = blockIdx.x; tile < nTiles; tile += gridDim.x) {
        int row0 = tile * 64;

        #pragma unroll
        for (int i = 0; i < 4; ++i) {
            int idx = i * 256 + t;
            int row = idx >> 4;
            int chunk = idx & 15;
            int grow = row0 + row;
            if (grow >= N) grow = N - 1;
            *(f16x8*)&ldsS[row * LSTRIDE + chunk * 8] = hv[(size_t)grow * 16 + chunk];
        }
        __syncthreads();

        #pragma unroll
        for (int r = 0; r < 4; ++r) {
            f16x8 afrag[4];
            #pragma unroll
            for (int s = 0; s < 4; ++s)
                afrag[s] = *(const f16x8*)&ldsS[(r*16 + c16) * LSTRIDE + (s*4 + quad) * 8];

            f32x4 acc[6];
            #pragma unroll
            for (int j = 0; j < 6; ++j) acc[j] = (f32x4){0.f, 0.f, 0.f, 0.f};
            #pragma unroll
            for (int s = 0; s < 4; ++s) {
                #pragma unroll
                for (int j = 0; j < 6; ++j)
                    acc[j] = __builtin_amdgcn_mfma_f32_16x16x32_f16(afrag[s], bfrag[j][s], acc[j], 0, 0, 0);
            }

            float wsv[4];
            #pragma unroll
            for (int reg = 0; reg < 4; ++reg) {
                int gr = row0 + r*16 + quad*4 + reg;
                wsv[reg] = wsum[(gr < N) ? gr : (N - 1)];
            }
            #pragma unroll
            for (int j = 0; j < 2; ++j) {
                int col = (2*wave + j) * 16 + c16;
                #pragma unroll
                for (int reg = 0; reg < 4; ++reg) {
                    int lr = r*16 + quad*4 + reg;
                    lds_a[lr * LSTRIDE + col] = (_Float16)(acc[j][reg] + bb1[j]);
                    lds_d[lr * LSTRIDE + col] =
                        (_Float16)(acc[4+j][reg] + bb3[j] - wsv[reg] * acc[2+j][reg]);
                }
            }
        }
        __syncthreads();

        #pragma unroll
        for (int i = 0; i < 4; ++i) {
            int idx = i * 256 + t;
            int row = idx >> 4;
            int c8  = idx & 15;
            int grow = row0 + row;
            if (grow < N) {
                f16x8 va = *(const f16x8*)&lds_a[row * LSTRIDE + c8 * 8];
                oa[(size_t)grow * 16 + c8] = va;
                f16x8 vd = *(const f16x8*)&lds_d[row * LSTRIDE + c8 * 8];
                od[(size_t)grow * 16 + c8] = vd;
            }
        }
        __syncthreads();
    }
}

// Variant 2 (layer 1): reads fp32 x and fuses standardization into staging.

__global__ __launch_bounds__(256, 2) void gemm_mfma_std_kernel(
    const float* __restrict__ x,
    const float* __restrict__ meanp, const float* __restrict__ rstdp,
    int N, int nTiles,
    const _Float16* __restrict__ Wt,
    const float* __restrict__ b1,
    const float* __restrict__ b3,
    const float* __restrict__ wsum,
    _Float16* __restrict__ out_a, _Float16* __restrict__ out_d)
{
    __shared__ _Float16 ldsS[64 * LSTRIDE];
    __shared__ _Float16 lds_a[64 * LSTRIDE];
    __shared__ _Float16 lds_d[64 * LSTRIDE];

    int t = threadIdx.x;
    int wave = t >> 6;
    int lane = t & 63;
    int quad = lane >> 4;
    int c16  = lane & 15;

    const f16x8* wv = (const f16x8*)Wt;
    int ntl[6] = {2*wave, 2*wave+1, 8+2*wave, 9+2*wave, 16+2*wave, 17+2*wave};
    f16x8 bfrag[6][4];
    #pragma unroll
    for (int j = 0; j < 6; ++j) {
        int nrow = ntl[j] * 16 + c16;
        #pragma unroll
        for (int s = 0; s < 4; ++s)
            bfrag[j][s] = wv[(size_t)nrow * 16 + s * 4 + quad];
    }
    float bb1[2], bb3[2];
    #pragma unroll
    for (int j = 0; j < 2; ++j) {
        int col = (2*wave + j) * 16 + c16;
        bb1[j] = b1[col];
        bb3[j] = b3[col];
    }

    // per-thread column group for staging: columns 4*(t&31) .. +3
    int c4 = t & 31;
    float4 mu = ((const float4*)meanp)[c4];
    float4 rs = ((const float4*)rstdp)[c4];

    const float4* xv = (const float4*)x;   // row stride 32 float4
    f16x8* oa = (f16x8*)out_a;
    f16x8* od = (f16x8*)out_d;

    for (int tile = blockIdx.x; tile < nTiles; tile += gridDim.x) {
        int row0 = tile * 64;

        // stage: 64 rows x 32 float4 = 2048 reads; 8 per thread, coalesced
        #pragma unroll
        for (int i = 0; i < 8; ++i) {
            int idx = i * 256 + t;        // 0..2047
            int row = idx >> 5;           // 0..63 (since idx&31 == t&31 == c4)
            int grow = row0 + row;
            if (grow >= N) grow = N - 1;
            float4 v = xv[(size_t)grow * 32 + c4];
            f16x4 o;
            o.x = (_Float16)((v.x - mu.x) * rs.x);
            o.y = (_Float16)((v.y - mu.y) * rs.y);
            o.z = (_Float16)((v.z - mu.z) * rs.z);
            o.w = (_Float16)((v.w - mu.w) * rs.w);
            *(f16x4*)&ldsS[row * LSTRIDE + c4 * 4] = o;
        }
        __syncthreads();

        #pragma unroll
        for (int r = 0; r < 4; ++r) {
            f16x8 afrag[4];
            #pragma unroll
            for (int s = 0; s < 4; ++s)
                afrag[s] = *(const f16x8*)&ldsS[(r*16 + c16) * LSTRIDE + (s*4 + quad) * 8];

            f32x4 acc[6];
            #pragma unroll
            for (int j = 0; j < 6; ++j) acc[j] = (f32x4){0.f, 0.f, 0.f, 0.f};
            #pragma unroll
            for (int s = 0; s < 4; ++s) {
                #pragma unroll
                for (int j = 0; j < 6; ++j)
                    acc[j] = __builtin_amdgcn_mfma_f32_16x16x32_f16(afrag[s], bfrag[j][s], acc[j], 0, 0, 0);
            }

            float wsv[4];
            #pragma unroll
            for (int reg = 0; reg < 4; ++reg) {
                int gr = row0 + r*16 + quad*4 + reg;
                wsv[reg] = wsum[(gr < N) ? gr : (N - 1)];
            }
            #pragma unroll
            for (int j = 0; j < 2; ++j) {
                int col = (2*wave + j) * 16 + c16;
                #pragma unroll
                for (int reg = 0; reg < 4; ++reg) {
                    int lr = r*16 + quad*4 + reg;
                    lds_a[lr * LSTRIDE + col] = (_Float16)(acc[j][reg] + bb1[j]);
                    lds_d[lr * LSTRIDE + col] =
                        (_Float16)(acc[4+j][reg] + bb3[j] - wsv[reg] * acc[2+j][reg]);
                }
            }
        }
        __syncthreads();

        #pragma unroll
        for (int i = 0; i < 4; ++i) {
            int idx = i * 256 + t;
            int row = idx >> 4;
            int c8  = idx & 15;
            int grow = row0 + row;
            if (grow < N) {
                f16x8 va = *(const f16x8*)&lds_a[row * LSTRIDE + c8 * 8];
                oa[(size_t)grow * 16 + c8] = va;
                f16x8 vd = *(const f16x8*)&lds_d[row * LSTRIDE + c8 * 8];
                od[(size_t)grow * 16 + c8] = vd;
            }
        }
        __syncthreads();
    }
}

// ===================== fused gather + LN + leaky =====================
// 1 node per wave; 4 edge-groups x 16 lanes x f16x8 (16B/lane).

__global__ __launch_bounds__(256) void aggregate_ln_kernel(
    const int* __restrict__ rowptr, const int2* __restrict__ csr,
    const _Float16* __restrict__ a, const _Float16* __restrict__ d,
    const float* __restrict__ g, const float* __restrict__ beta,
    _Float16* __restrict__ out, int N)
{
    int wave = threadIdx.x >> 6;
    int lane = threadIdx.x & 63;
    int grp  = lane >> 4;        // 0..3: edge group
    int l    = lane & 15;        // feature chunk: cols 8l..8l+7
    int node = blockIdx.x * 4 + wave;
    if (node >= N) return;
    int b = rowptr[node], en = rowptr[node + 1];
    int deg = en - b;

    const f16x8* av = (const f16x8*)a;   // row stride 16 chunks
    float acc[8] = {0,0,0,0,0,0,0,0};

    int nk = (deg + 3) >> 2;             // edge e = b + k*4 + grp
    int k = 0;
    for (; k + 4 <= nk; k += 4) {        // 16 edge-rows in flight
        int2 p[4];
        #pragma unroll
        for (int j = 0; j < 4; ++j) {
            int idx = b + (k + j) * 4 + grp;
            int idc = (idx < en) ? idx : b;
            p[j] = csr[idc];
            if (idx >= en) p[j].y = 0;
        }
        f16x8 v[4];
        #pragma unroll
        for (int j = 0; j < 4; ++j)
            v[j] = av[(size_t)p[j].x * 16 + l];
        #pragma unroll
        for (int j = 0; j < 4; ++j) {
            float w = __int_as_float(p[j].y);
            #pragma unroll
            for (int i = 0; i < 8; ++i) acc[i] += w * (float)v[j][i];
        }
    }
    for (; k < nk; ++k) {
        int idx = b + k * 4 + grp;
        int idc = (idx < en) ? idx : b;
        int2 p = csr[idc];
        if (idx >= en) p.y = 0;
        f16x8 v = av[(size_t)p.x * 16 + l];
        float w = __int_as_float(p.y);
        #pragma unroll
        for (int i = 0; i < 8; ++i) acc[i] += w * (float)v[i];
    }

    #pragma unroll
    for (int i = 0; i < 8; ++i) {
        acc[i] += __shfl_xor(acc[i], 16, 64);
        acc[i] += __shfl_xor(acc[i], 32, 64);
    }

    f16x8 dv = ((const f16x8*)d)[(size_t)node * 16 + l];
    float v[8];
    float s = 0.f, ss = 0.f;
    #pragma unroll
    for (int i = 0; i < 8; ++i) {
        v[i] = acc[i] + (float)dv[i];
        s += v[i]; ss += v[i] * v[i];
    }
    #pragma unroll
    for (int off = 1; off <= 8; off <<= 1) {
        s  += __shfl_xor(s,  off, 64);
        ss += __shfl_xor(ss, off, 64);
    }
    float mean = s * (1.f / 128.f);
    float var = ss * (1.f / 128.f) - mean * mean;
    float rstd = rsqrtf(var + 1e-5f);

    const float4* gv4 = (const float4*)g;
    const float4* bv4 = (const float4*)beta;
    float4 ga = gv4[l*2], gb = gv4[l*2+1];
    float4 ba = bv4[l*2], bb = bv4[l*2+1];
    float go[8] = {ga.x,ga.y,ga.z,ga.w,gb.x,gb.y,gb.z,gb.w};
    float bo[8] = {ba.x,ba.y,ba.z,ba.w,bb.x,bb.y,bb.z,bb.w};
    f16x8 ov;
    #pragma unroll
    for (int i = 0; i < 8; ++i) {
        float o = (v[i] - mean) * rstd * go[i] + bo[i];
        o = o >= 0.f ? o : 0.1f * o;
        ov[i] = (_Float16)o;
    }
    if (grp == 0)
        ((f16x8*)out)[(size_t)node * 16 + l] = ov;
}

// ===================== output layer (D_OUT=1) =====================

__global__ __launch_bounds__(256) void out_gemv_kernel(
    const _Float16* __restrict__ h, int N,
    const float* __restrict__ W1, const float* __restrict__ b1,
    const float* __restrict__ W2,
    const float* __restrict__ W3, const float* __restrict__ b3,
    const float* __restrict__ wsum,
    float* __restrict__ a1, float* __restrict__ dpart)
{
    int wave = threadIdx.x >> 6;
    int lane = threadIdx.x & 63;
    int node = blockIdx.x * 4 + wave;
    if (node >= N) return;
    const _Float16* row = h + (size_t)node * 128;
    float h0 = (float)row[lane], h1 = (float)row[lane + 64];
    float s1 = wave_reduce_sum(h0 * W1[lane] + h1 * W1[lane + 64]);
    float s2 = wave_reduce_sum(h0 * W2[lane] + h1 * W2[lane + 64]);
    float s3 = wave_reduce_sum(h0 * W3[lane] + h1 * W3[lane + 64]);
    if (lane == 0) {
        a1[node] = s1 + b1[0];
        dpart[node] = s3 + b3[0] - wsum[node] * s2;
    }
}

__global__ __launch_bounds__(256) void gather_out_kernel(
    const int* __restrict__ rowptr, const int2* __restrict__ csr,
    const float* __restrict__ a1, const float* __restrict__ dpart,
    float* __restrict__ out, int N)
{
    int n = blockIdx.x * 256 + threadIdx.x;
    if (n >= N) return;
    int b = rowptr[n], en = rowptr[n + 1];
    float s = dpart[n];
    int e = b;
    for (; e + 4 <= en; e += 4) {
        int2 p0 = csr[e], p1 = csr[e+1], p2 = csr[e+2], p3 = csr[e+3];
        float x0 = a1[p0.x], x1 = a1[p1.x], x2 = a1[p2.x], x3 = a1[p3.x];
        s += __int_as_float(p0.y) * x0 + __int_as_float(p1.y) * x1
           + __int_as_float(p2.y) * x2 + __int_as_float(p3.y) * x3;
    }
    for (; e < en; ++e) {
        int2 p = csr[e];
        s += __int_as_float(p.y) * a1[p.x];
    }
    out[n] = 1.f / (1.f + expf(-s));
}

// ---------------------------------------------------------------------------
extern "C" void kernel_launch(void* const* d_in, const int* in_sizes, int n_in,
                              void* d_out, int out_size, void* d_ws, size_t ws_size,
                              hipStream_t stream)
{
    const float* x     = (const float*)d_in[0];
    const float* ew    = (const float*)d_in[1];
    const float* W1_in = (const float*)d_in[2];
    const float* b1_in = (const float*)d_in[3];
    const float* W2_in = (const float*)d_in[4];
    const float* W3_in = (const float*)d_in[5];
    const float* b3_in = (const float*)d_in[6];
    const float* W1_h  = (const float*)d_in[7];
    const float* b1_h  = (const float*)d_in[8];
    const float* W2_h  = (const float*)d_in[9];
    const float* W3_h  = (const float*)d_in[10];
    const float* b3_h  = (const float*)d_in[11];
    const float* W1_o  = (const float*)d_in[12];
    const float* b1_o  = (const float*)d_in[13];
    const float* W2_o  = (const float*)d_in[14];
    const float* W3_o  = (const float*)d_in[15];
    const float* b3_o  = (const float*)d_in[16];
    const float* g1    = (const float*)d_in[17];
    const float* beta1 = (const float*)d_in[18];
    const float* g2    = (const float*)d_in[19];
    const float* beta2 = (const float*)d_in[20];
    const int*   eidx  = (const int*)d_in[21];

    const int N = in_sizes[0] / 128;
    const int E = in_sizes[1];
    const int* srcp = eidx;
    const int* dstp = eidx + E;

    // ---- workspace carve-out (256B-aligned chunks) ----
    size_t off = 0;
    auto carve = [&](size_t nbytes) -> void* {
        void* p = (char*)d_ws + off;
        off += (nbytes + 255) & ~(size_t)255;
        return p;
    };
    // zero-init region first: deg, stats, wsum contiguous -> one memset
    int*      deg    = (int*)     carve((size_t)N * 4);
    float*    stats  = (float*)   carve(256 * 4);
    float*    wsum   = (float*)   carve((size_t)N * 4);
    size_t zeroBytes = off;                       // everything carved so far
    _Float16* buf_h  = (_Float16*)carve((size_t)N * 128 * 2);
    _Float16* buf_a  = (_Float16*)carve((size_t)N * 128 * 2);
    _Float16* buf_d  = (_Float16*)carve((size_t)N * 128 * 2);
    int2*     csr    = (int2*)    carve((size_t)E * 8);
    _Float16* Wt_in  = (_Float16*)carve(384 * 128 * 2);
    _Float16* Wt_h   = (_Float16*)carve(384 * 128 * 2);
    int*      rowptr = (int*)     carve((size_t)(N + 1) * 4);
    int*      fill   = (int*)     carve((size_t)N * 4);
    int*      partial= (int*)     carve(256 * 4);
    float*    meanp  = (float*)   carve(128 * 4);
    float*    rstdp  = (float*)   carve(128 * 4);
    float*    a1     = (float*)   carve((size_t)N * 4);
    float*    dpart  = (float*)   carve((size_t)N * 4);

    const int nodeWaveBlocks = (N + 3) / 4;
    const int eBlocks = (E + 255) / 256;
    const int nBlocks = (N + 255) / 256;
    const int nb = (N + 1023) / 1024;
    const int wBlocks = (2 * 384 * 128 + 255) / 256;

    hipMemsetAsync(deg, 0, zeroBytes, stream);    // deg + stats + wsum

    // ---- CSR build (wsum fused into fill) + weight conversion ----
    hist_kernel<<<eBlocks, 256, 0, stream>>>(dstp, deg, E);
    scan_pass1<<<nb, 256, 0, stream>>>(deg, N, partial);
    scan_pass2<<<1, 256, 0, stream>>>(partial, nb);
    scan_pass3<<<nb, 256, 0, stream>>>(deg, N, partial, rowptr, fill, E);
    csr_fill_kernel<<<eBlocks, 256, 0, stream>>>(srcp, dstp, ew, fill, csr, wsum, E);
    convert_weights_kernel<<<wBlocks, 256, 0, stream>>>(
        W1_in, W2_in, W3_in, Wt_in, W1_h, W2_h, W3_h, Wt_h);

    // ---- input standardization stats ----
    colstats_kernel<<<CS_BLOCKS, 256, 0, stream>>>(x, N, stats);
    finalize_stats_kernel<<<1, 128, 0, stream>>>(stats, N, meanp, rstdp);

    const int nTiles = (N + 63) / 64;
    const int gemmGrid = (nTiles < 512) ? nTiles : 512;

    // ---- layer 1 (standardize fused into GEMM staging) ----
    gemm_mfma_std_kernel<<<gemmGrid, 256, 0, stream>>>(
        x, meanp, rstdp, N, nTiles, Wt_in, b1_in, b3_in, wsum, buf_a, buf_d);
    aggregate_ln_kernel<<<nodeWaveBlocks, 256, 0, stream>>>(rowptr, csr, buf_a, buf_d, g1, beta1, buf_h, N);

    // ---- layers 2..3 ----
    for (int l = 0; l < 2; ++l) {
        gemm_mfma_kernel<<<gemmGrid, 256, 0, stream>>>(buf_h, N, nTiles, Wt_h, b1_h, b3_h, wsum, buf_a, buf_d);
        aggregate_ln_kernel<<<nodeWaveBlocks, 256, 0, stream>>>(rowptr, csr, buf_a, buf_d, g2, beta2, buf_h, N);
    }

    // ---- output layer ----
    out_gemv_kernel<<<nodeWaveBlocks, 256, 0, stream>>>(buf_h, N, W1_o, b1_o, W2_o, W3_o, b3_o, wsum, a1, dpart);
    gather_out_kernel<<<nBlocks, 256, 0, stream>>>(rowptr, csr, a1, dpart, (float*)d_out, N);
}

// Round 10
// 402.704 us; speedup vs baseline: 1.0498x; 1.0498x over previous
//
#include <hip/hip_runtime.h>
#include <hip/hip_bf16.h>
#include <math.h>

// ---------------------------------------------------------------------------
// GNN_72103910966081: 4-layer LEConv GNN, N=50000, E=600000, D=128.
// Round 10: revert R9's wsum-into-csr_fill fusion (stacked dependent atomics
// made csr_fill 62us; standalone wsum_csr is ~4us). Keep the good R9 fusions:
// standardize-in-gemm staging, merged weight convert, atomic colstats.
// ---------------------------------------------------------------------------

typedef _Float16 f16x8 __attribute__((ext_vector_type(8)));
typedef _Float16 f16x4 __attribute__((ext_vector_type(4)));
typedef float f32x4 __attribute__((ext_vector_type(4)));

#define LSTRIDE 136   // halves per LDS row: 128 + 8 (16B-aligned, breaks 2^k banks)

__device__ inline float wave_reduce_sum(float v) {
    #pragma unroll
    for (int off = 32; off > 0; off >>= 1)
        v += __shfl_xor(v, off, 64);
    return v;
}

// ===================== CSR build =====================

__global__ __launch_bounds__(256) void hist_kernel(
    const int* __restrict__ dst, int* __restrict__ deg, int E)
{
    int e = blockIdx.x * 256 + threadIdx.x;
    if (e < E) atomicAdd(&deg[dst[e]], 1);
}

__global__ __launch_bounds__(256) void scan_pass1(
    const int* __restrict__ deg, int N, int* __restrict__ partial)
{
    __shared__ int sh[256];
    int t = threadIdx.x;
    int base = blockIdx.x * 1024 + t * 4;
    int s = 0;
    #pragma unroll
    for (int i = 0; i < 4; ++i) { int idx = base + i; if (idx < N) s += deg[idx]; }
    sh[t] = s; __syncthreads();
    for (int off = 128; off > 0; off >>= 1) {
        if (t < off) sh[t] += sh[t + off];
        __syncthreads();
    }
    if (t == 0) partial[blockIdx.x] = sh[0];
}

__global__ __launch_bounds__(256) void scan_pass2(int* __restrict__ partial, int nb)
{
    __shared__ int sh[256];
    int t = threadIdx.x;
    sh[t] = (t < nb) ? partial[t] : 0;
    __syncthreads();
    for (int off = 1; off < 256; off <<= 1) {
        int x = sh[t];
        if (t >= off) x += sh[t - off];
        __syncthreads();
        sh[t] = x;
        __syncthreads();
    }
    if (t < nb) partial[t] = (t > 0) ? sh[t - 1] : 0;   // exclusive
}

__global__ __launch_bounds__(256) void scan_pass3(
    const int* __restrict__ deg, int N, const int* __restrict__ partial,
    int* __restrict__ rowptr, int* __restrict__ fill, int E)
{
    __shared__ int sh[256];
    int t = threadIdx.x;
    int base = blockIdx.x * 1024 + t * 4;
    int v[4]; int s = 0;
    #pragma unroll
    for (int i = 0; i < 4; ++i) { int idx = base + i; v[i] = (idx < N) ? deg[idx] : 0; s += v[i]; }
    sh[t] = s; __syncthreads();
    for (int off = 1; off < 256; off <<= 1) {
        int x = sh[t];
        if (t >= off) x += sh[t - off];
        __syncthreads();
        sh[t] = x;
        __syncthreads();
    }
    int off0 = partial[blockIdx.x] + ((t > 0) ? sh[t - 1] : 0);
    #pragma unroll
    for (int i = 0; i < 4; ++i) {
        int idx = base + i;
        if (idx < N) { rowptr[idx] = off0; fill[idx] = off0; off0 += v[i]; }
    }
    if (blockIdx.x == 0 && t == 0) rowptr[N] = E;
}

// single int atomic + 8B scatter (R8 form — do NOT stack a second atomic here)
__global__ __launch_bounds__(256) void csr_fill_kernel(
    const int* __restrict__ src, const int* __restrict__ dst,
    const float* __restrict__ ew, int* __restrict__ fill,
    int2* __restrict__ csr, int E)
{
    int e = blockIdx.x * 256 + threadIdx.x;
    if (e >= E) return;
    int d = dst[e];
    int pos = atomicAdd(&fill[d], 1);
    csr[pos] = make_int2(src[e], __float_as_int(ew[e]));
}

__global__ __launch_bounds__(256) void wsum_csr_kernel(
    const int* __restrict__ rowptr, const int2* __restrict__ csr,
    float* __restrict__ wsum, int N)
{
    int n = blockIdx.x * 256 + threadIdx.x;
    if (n >= N) return;
    int b = rowptr[n], en = rowptr[n + 1];
    float s = 0.f;
    for (int e = b; e < en; ++e) s += __int_as_float(csr[e].y);
    wsum[n] = s;
}

// ===================== weight convert+transpose (both sets, one launch) ====

__global__ __launch_bounds__(256) void convert_weights_kernel(
    const float* __restrict__ W1a, const float* __restrict__ W2a,
    const float* __restrict__ W3a, _Float16* __restrict__ Wta,
    const float* __restrict__ W1b, const float* __restrict__ W2b,
    const float* __restrict__ W3b, _Float16* __restrict__ Wtb)
{
    int idx = blockIdx.x * 256 + threadIdx.x;   // over 2*384*128
    if (idx >= 2 * 384 * 128) return;
    int set = idx >= 384 * 128;
    int id = idx - set * 384 * 128;
    int n = id >> 7, k = id & 127;
    const float* W = set ? ((n < 128) ? W1b : (n < 256) ? W2b : W3b)
                         : ((n < 128) ? W1a : (n < 256) ? W2a : W3a);
    _Float16* Wt = set ? Wtb : Wta;
    int c = n & 127;
    Wt[id] = (_Float16)W[k * 128 + c];
}

// ===================== input standardization stats =====================

#define CS_BLOCKS 512

__global__ __launch_bounds__(256) void colstats_kernel(
    const float* __restrict__ x, int N, float* __restrict__ stats)
{
    __shared__ float shs[256][4];
    __shared__ float shq[256][4];
    int t = threadIdx.x;
    int g = t >> 5;
    int c = t & 31;
    const float4* xv = (const float4*)x;    // row stride 32
    float s0=0.f,s1=0.f,s2=0.f,s3=0.f, q0=0.f,q1=0.f,q2=0.f,q3=0.f;
    for (int r = blockIdx.x * 8 + g; r < N; r += CS_BLOCKS * 8) {
        float4 v = xv[(size_t)r * 32 + c];
        s0 += v.x; s1 += v.y; s2 += v.z; s3 += v.w;
        q0 += v.x*v.x; q1 += v.y*v.y; q2 += v.z*v.z; q3 += v.w*v.w;
    }
    shs[t][0]=s0; shs[t][1]=s1; shs[t][2]=s2; shs[t][3]=s3;
    shq[t][0]=q0; shq[t][1]=q1; shq[t][2]=q2; shq[t][3]=q3;
    __syncthreads();
    if (t < 32) {
        float S[4] = {0,0,0,0}, Q[4] = {0,0,0,0};
        #pragma unroll
        for (int gg = 0; gg < 8; ++gg) {
            #pragma unroll
            for (int i = 0; i < 4; ++i) {
                S[i] += shs[t + 32*gg][i];
                Q[i] += shq[t + 32*gg][i];
            }
        }
        #pragma unroll
        for (int i = 0; i < 4; ++i) {
            atomicAdd(&stats[t*4 + i], S[i]);
            atomicAdd(&stats[128 + t*4 + i], Q[i]);
        }
    }
}

__global__ void finalize_stats_kernel(const float* __restrict__ stats, int N,
                                      float* __restrict__ mean,
                                      float* __restrict__ rstd)
{
    int f = threadIdx.x;  // 128 threads
    float s = stats[f], ss = stats[128 + f];
    float m = s / (float)N;
    float var = (ss - s * s / (float)N) / (float)(N - 1);  // ddof=1
    var = fmaxf(var, 0.f);
    mean[f] = m;
    rstd[f] = 1.f / (sqrtf(var) + 1e-6f);
}

// ===================== MFMA fused GEMM (persistent, B in registers) ========
// Variant 1: reads fp16 h (layers 2..3).

__global__ __launch_bounds__(256, 2) void gemm_mfma_kernel(
    const _Float16* __restrict__ h, int N, int nTiles,
    const _Float16* __restrict__ Wt,
    const float* __restrict__ b1,
    const float* __restrict__ b3,
    const float* __restrict__ wsum,
    _Float16* __restrict__ out_a, _Float16* __restrict__ out_d)
{
    __shared__ _Float16 ldsS[64 * LSTRIDE];
    __shared__ _Float16 lds_a[64 * LSTRIDE];
    __shared__ _Float16 lds_d[64 * LSTRIDE];

    int t = threadIdx.x;
    int wave = t >> 6;
    int lane = t & 63;
    int quad = lane >> 4;
    int c16  = lane & 15;

    const f16x8* wv = (const f16x8*)Wt;
    int ntl[6] = {2*wave, 2*wave+1, 8+2*wave, 9+2*wave, 16+2*wave, 17+2*wave};
    f16x8 bfrag[6][4];
    #pragma unroll
    for (int j = 0; j < 6; ++j) {
        int nrow = ntl[j] * 16 + c16;
        #pragma unroll
        for (int s = 0; s < 4; ++s)
            bfrag[j][s] = wv[(size_t)nrow * 16 + s * 4 + quad];
    }
    float bb1[2], bb3[2];
    #pragma unroll
    for (int j = 0; j < 2; ++j) {
        int col = (2*wave + j) * 16 + c16;
        bb1[j] = b1[col];
        bb3[j] = b3[col];
    }

    const f16x8* hv = (const f16x8*)h;
    f16x8* oa = (f16x8*)out_a;
    f16x8* od = (f16x8*)out_d;

    for (int tile = blockIdx.x; tile < nTiles; tile += gridDim.x) {
        int row0 = tile * 64;

        #pragma unroll
        for (int i = 0; i < 4; ++i) {
            int idx = i * 256 + t;
            int row = idx >> 4;
            int chunk = idx & 15;
            int grow = row0 + row;
            if (grow >= N) grow = N - 1;
            *(f16x8*)&ldsS[row * LSTRIDE + chunk * 8] = hv[(size_t)grow * 16 + chunk];
        }
        __syncthreads();

        #pragma unroll
        for (int r = 0; r < 4; ++r) {
            f16x8 afrag[4];
            #pragma unroll
            for (int s = 0; s < 4; ++s)
                afrag[s] = *(const f16x8*)&ldsS[(r*16 + c16) * LSTRIDE + (s*4 + quad) * 8];

            f32x4 acc[6];
            #pragma unroll
            for (int j = 0; j < 6; ++j) acc[j] = (f32x4){0.f, 0.f, 0.f, 0.f};
            #pragma unroll
            for (int s = 0; s < 4; ++s) {
                #pragma unroll
                for (int j = 0; j < 6; ++j)
                    acc[j] = __builtin_amdgcn_mfma_f32_16x16x32_f16(afrag[s], bfrag[j][s], acc[j], 0, 0, 0);
            }

            float wsv[4];
            #pragma unroll
            for (int reg = 0; reg < 4; ++reg) {
                int gr = row0 + r*16 + quad*4 + reg;
                wsv[reg] = wsum[(gr < N) ? gr : (N - 1)];
            }
            #pragma unroll
            for (int j = 0; j < 2; ++j) {
                int col = (2*wave + j) * 16 + c16;
                #pragma unroll
                for (int reg = 0; reg < 4; ++reg) {
                    int lr = r*16 + quad*4 + reg;
                    lds_a[lr * LSTRIDE + col] = (_Float16)(acc[j][reg] + bb1[j]);
                    lds_d[lr * LSTRIDE + col] =
                        (_Float16)(acc[4+j][reg] + bb3[j] - wsv[reg] * acc[2+j][reg]);
                }
            }
        }
        __syncthreads();

        #pragma unroll
        for (int i = 0; i < 4; ++i) {
            int idx = i * 256 + t;
            int row = idx >> 4;
            int c8  = idx & 15;
            int grow = row0 + row;
            if (grow < N) {
                f16x8 va = *(const f16x8*)&lds_a[row * LSTRIDE + c8 * 8];
                oa[(size_t)grow * 16 + c8] = va;
                f16x8 vd = *(const f16x8*)&lds_d[row * LSTRIDE + c8 * 8];
                od[(size_t)grow * 16 + c8] = vd;
            }
        }
        __syncthreads();
    }
}

// Variant 2 (layer 1): reads fp32 x and fuses standardization into staging.

__global__ __launch_bounds__(256, 2) void gemm_mfma_std_kernel(
    const float* __restrict__ x,
    const float* __restrict__ meanp, const float* __restrict__ rstdp,
    int N, int nTiles,
    const _Float16* __restrict__ Wt,
    const float* __restrict__ b1,
    const float* __restrict__ b3,
    const float* __restrict__ wsum,
    _Float16* __restrict__ out_a, _Float16* __restrict__ out_d)
{
    __shared__ _Float16 ldsS[64 * LSTRIDE];
    __shared__ _Float16 lds_a[64 * LSTRIDE];
    __shared__ _Float16 lds_d[64 * LSTRIDE];

    int t = threadIdx.x;
    int wave = t >> 6;
    int lane = t & 63;
    int quad = lane >> 4;
    int c16  = lane & 15;

    const f16x8* wv = (const f16x8*)Wt;
    int ntl[6] = {2*wave, 2*wave+1, 8+2*wave, 9+2*wave, 16+2*wave, 17+2*wave};
    f16x8 bfrag[6][4];
    #pragma unroll
    for (int j = 0; j < 6; ++j) {
        int nrow = ntl[j] * 16 + c16;
        #pragma unroll
        for (int s = 0; s < 4; ++s)
            bfrag[j][s] = wv[(size_t)nrow * 16 + s * 4 + quad];
    }
    float bb1[2], bb3[2];
    #pragma unroll
    for (int j = 0; j < 2; ++j) {
        int col = (2*wave + j) * 16 + c16;
        bb1[j] = b1[col];
        bb3[j] = b3[col];
    }

    int c4 = t & 31;
    float4 mu = ((const float4*)meanp)[c4];
    float4 rs = ((const float4*)rstdp)[c4];

    const float4* xv = (const float4*)x;   // row stride 32 float4
    f16x8* oa = (f16x8*)out_a;
    f16x8* od = (f16x8*)out_d;

    for (int tile = blockIdx.x; tile < nTiles; tile += gridDim.x) {
        int row0 = tile * 64;

        #pragma unroll
        for (int i = 0; i < 8; ++i) {
            int idx = i * 256 + t;        // 0..2047
            int row = idx >> 5;           // 0..63
            int grow = row0 + row;
            if (grow >= N) grow = N - 1;
            float4 v = xv[(size_t)grow * 32 + c4];
            f16x4 o;
            o.x = (_Float16)((v.x - mu.x) * rs.x);
            o.y = (_Float16)((v.y - mu.y) * rs.y);
            o.z = (_Float16)((v.z - mu.z) * rs.z);
            o.w = (_Float16)((v.w - mu.w) * rs.w);
            *(f16x4*)&ldsS[row * LSTRIDE + c4 * 4] = o;
        }
        __syncthreads();

        #pragma unroll
        for (int r = 0; r < 4; ++r) {
            f16x8 afrag[4];
            #pragma unroll
            for (int s = 0; s < 4; ++s)
                afrag[s] = *(const f16x8*)&ldsS[(r*16 + c16) * LSTRIDE + (s*4 + quad) * 8];

            f32x4 acc[6];
            #pragma unroll
            for (int j = 0; j < 6; ++j) acc[j] = (f32x4){0.f, 0.f, 0.f, 0.f};
            #pragma unroll
            for (int s = 0; s < 4; ++s) {
                #pragma unroll
                for (int j = 0; j < 6; ++j)
                    acc[j] = __builtin_amdgcn_mfma_f32_16x16x32_f16(afrag[s], bfrag[j][s], acc[j], 0, 0, 0);
            }

            float wsv[4];
            #pragma unroll
            for (int reg = 0; reg < 4; ++reg) {
                int gr = row0 + r*16 + quad*4 + reg;
                wsv[reg] = wsum[(gr < N) ? gr : (N - 1)];
            }
            #pragma unroll
            for (int j = 0; j < 2; ++j) {
                int col = (2*wave + j) * 16 + c16;
                #pragma unroll
                for (int reg = 0; reg < 4; ++reg) {
                    int lr = r*16 + quad*4 + reg;
                    lds_a[lr * LSTRIDE + col] = (_Float16)(acc[j][reg] + bb1[j]);
                    lds_d[lr * LSTRIDE + col] =
                        (_Float16)(acc[4+j][reg] + bb3[j] - wsv[reg] * acc[2+j][reg]);
                }
            }
        }
        __syncthreads();

        #pragma unroll
        for (int i = 0; i < 4; ++i) {
            int idx = i * 256 + t;
            int row = idx >> 4;
            int c8  = idx & 15;
            int grow = row0 + row;
            if (grow < N) {
                f16x8 va = *(const f16x8*)&lds_a[row * LSTRIDE + c8 * 8];
                oa[(size_t)grow * 16 + c8] = va;
                f16x8 vd = *(const f16x8*)&lds_d[row * LSTRIDE + c8 * 8];
                od[(size_t)grow * 16 + c8] = vd;
            }
        }
        __syncthreads();
    }
}

// ===================== fused gather + LN + leaky =====================
// 1 node per wave; 4 edge-groups x 16 lanes x f16x8 (16B/lane).

__global__ __launch_bounds__(256) void aggregate_ln_kernel(
    const int* __restrict__ rowptr, const int2* __restrict__ csr,
    const _Float16* __restrict__ a, const _Float16* __restrict__ d,
    const float* __restrict__ g, const float* __restrict__ beta,
    _Float16* __restrict__ out, int N)
{
    int wave = threadIdx.x >> 6;
    int lane = threadIdx.x & 63;
    int grp  = lane >> 4;        // 0..3: edge group
    int l    = lane & 15;        // feature chunk: cols 8l..8l+7
    int node = blockIdx.x * 4 + wave;
    if (node >= N) return;
    int b = rowptr[node], en = rowptr[node + 1];
    int deg = en - b;

    const f16x8* av = (const f16x8*)a;   // row stride 16 chunks
    float acc[8] = {0,0,0,0,0,0,0,0};

    int nk = (deg + 3) >> 2;             // edge e = b + k*4 + grp
    int k = 0;
    for (; k + 4 <= nk; k += 4) {        // 16 edge-rows in flight
        int2 p[4];
        #pragma unroll
        for (int j = 0; j < 4; ++j) {
            int idx = b + (k + j) * 4 + grp;
            int idc = (idx < en) ? idx : b;
            p[j] = csr[idc];
            if (idx >= en) p[j].y = 0;
        }
        f16x8 v[4];
        #pragma unroll
        for (int j = 0; j < 4; ++j)
            v[j] = av[(size_t)p[j].x * 16 + l];
        #pragma unroll
        for (int j = 0; j < 4; ++j) {
            float w = __int_as_float(p[j].y);
            #pragma unroll
            for (int i = 0; i < 8; ++i) acc[i] += w * (float)v[j][i];
        }
    }
    for (; k < nk; ++k) {
        int idx = b + k * 4 + grp;
        int idc = (idx < en) ? idx : b;
        int2 p = csr[idc];
        if (idx >= en) p.y = 0;
        f16x8 v = av[(size_t)p.x * 16 + l];
        float w = __int_as_float(p.y);
        #pragma unroll
        for (int i = 0; i < 8; ++i) acc[i] += w * (float)v[i];
    }

    #pragma unroll
    for (int i = 0; i < 8; ++i) {
        acc[i] += __shfl_xor(acc[i], 16, 64);
        acc[i] += __shfl_xor(acc[i], 32, 64);
    }

    f16x8 dv = ((const f16x8*)d)[(size_t)node * 16 + l];
    float v[8];
    float s = 0.f, ss = 0.f;
    #pragma unroll
    for (int i = 0; i < 8; ++i) {
        v[i] = acc[i] + (float)dv[i];
        s += v[i]; ss += v[i] * v[i];
    }
    #pragma unroll
    for (int off = 1; off <= 8; off <<= 1) {
        s  += __shfl_xor(s,  off, 64);
        ss += __shfl_xor(ss, off, 64);
    }
    float mean = s * (1.f / 128.f);
    float var = ss * (1.f / 128.f) - mean * mean;
    float rstd = rsqrtf(var + 1e-5f);

    const float4* gv4 = (const float4*)g;
    const float4* bv4 = (const float4*)beta;
    float4 ga = gv4[l*2], gb = gv4[l*2+1];
    float4 ba = bv4[l*2], bb = bv4[l*2+1];
    float go[8] = {ga.x,ga.y,ga.z,ga.w,gb.x,gb.y,gb.z,gb.w};
    float bo[8] = {ba.x,ba.y,ba.z,ba.w,bb.x,bb.y,bb.z,bb.w};
    f16x8 ov;
    #pragma unroll
    for (int i = 0; i < 8; ++i) {
        float o = (v[i] - mean) * rstd * go[i] + bo[i];
        o = o >= 0.f ? o : 0.1f * o;
        ov[i] = (_Float16)o;
    }
    if (grp == 0)
        ((f16x8*)out)[(size_t)node * 16 + l] = ov;
}

// ===================== output layer (D_OUT=1) =====================

__global__ __launch_bounds__(256) void out_gemv_kernel(
    const _Float16* __restrict__ h, int N,
    const float* __restrict__ W1, const float* __restrict__ b1,
    const float* __restrict__ W2,
    const float* __restrict__ W3, const float* __restrict__ b3,
    const float* __restrict__ wsum,
    float* __restrict__ a1, float* __restrict__ dpart)
{
    int wave = threadIdx.x >> 6;
    int lane = threadIdx.x & 63;
    int node = blockIdx.x * 4 + wave;
    if (node >= N) return;
    const _Float16* row = h + (size_t)node * 128;
    float h0 = (float)row[lane], h1 = (float)row[lane + 64];
    float s1 = wave_reduce_sum(h0 * W1[lane] + h1 * W1[lane + 64]);
    float s2 = wave_reduce_sum(h0 * W2[lane] + h1 * W2[lane + 64]);
    float s3 = wave_reduce_sum(h0 * W3[lane] + h1 * W3[lane + 64]);
    if (lane == 0) {
        a1[node] = s1 + b1[0];
        dpart[node] = s3 + b3[0] - wsum[node] * s2;
    }
}

__global__ __launch_bounds__(256) void gather_out_kernel(
    const int* __restrict__ rowptr, const int2* __restrict__ csr,
    const float* __restrict__ a1, const float* __restrict__ dpart,
    float* __restrict__ out, int N)
{
    int n = blockIdx.x * 256 + threadIdx.x;
    if (n >= N) return;
    int b = rowptr[n], en = rowptr[n + 1];
    float s = dpart[n];
    int e = b;
    for (; e + 4 <= en; e += 4) {
        int2 p0 = csr[e], p1 = csr[e+1], p2 = csr[e+2], p3 = csr[e+3];
        float x0 = a1[p0.x], x1 = a1[p1.x], x2 = a1[p2.x], x3 = a1[p3.x];
        s += __int_as_float(p0.y) * x0 + __int_as_float(p1.y) * x1
           + __int_as_float(p2.y) * x2 + __int_as_float(p3.y) * x3;
    }
    for (; e < en; ++e) {
        int2 p = csr[e];
        s += __int_as_float(p.y) * a1[p.x];
    }
    out[n] = 1.f / (1.f + expf(-s));
}

// ---------------------------------------------------------------------------
extern "C" void kernel_launch(void* const* d_in, const int* in_sizes, int n_in,
                              void* d_out, int out_size, void* d_ws, size_t ws_size,
                              hipStream_t stream)
{
    const float* x     = (const float*)d_in[0];
    const float* ew    = (const float*)d_in[1];
    const float* W1_in = (const float*)d_in[2];
    const float* b1_in = (const float*)d_in[3];
    const float* W2_in = (const float*)d_in[4];
    const float* W3_in = (const float*)d_in[5];
    const float* b3_in = (const float*)d_in[6];
    const float* W1_h  = (const float*)d_in[7];
    const float* b1_h  = (const float*)d_in[8];
    const float* W2_h  = (const float*)d_in[9];
    const float* W3_h  = (const float*)d_in[10];
    const float* b3_h  = (const float*)d_in[11];
    const float* W1_o  = (const float*)d_in[12];
    const float* b1_o  = (const float*)d_in[13];
    const float* W2_o  = (const float*)d_in[14];
    const float* W3_o  = (const float*)d_in[15];
    const float* b3_o  = (const float*)d_in[16];
    const float* g1    = (const float*)d_in[17];
    const float* beta1 = (const float*)d_in[18];
    const float* g2    = (const float*)d_in[19];
    const float* beta2 = (const float*)d_in[20];
    const int*   eidx  = (const int*)d_in[21];

    const int N = in_sizes[0] / 128;
    const int E = in_sizes[1];
    const int* srcp = eidx;
    const int* dstp = eidx + E;

    // ---- workspace carve-out (256B-aligned chunks) ----
    size_t off = 0;
    auto carve = [&](size_t nbytes) -> void* {
        void* p = (char*)d_ws + off;
        off += (nbytes + 255) & ~(size_t)255;
        return p;
    };
    // zero-init region first: deg + stats -> one memset
    int*      deg    = (int*)     carve((size_t)N * 4);
    float*    stats  = (float*)   carve(256 * 4);
    size_t zeroBytes = off;
    _Float16* buf_h  = (_Float16*)carve((size_t)N * 128 * 2);
    _Float16* buf_a  = (_Float16*)carve((size_t)N * 128 * 2);
    _Float16* buf_d  = (_Float16*)carve((size_t)N * 128 * 2);
    int2*     csr    = (int2*)    carve((size_t)E * 8);
    _Float16* Wt_in  = (_Float16*)carve(384 * 128 * 2);
    _Float16* Wt_h   = (_Float16*)carve(384 * 128 * 2);
    int*      rowptr = (int*)     carve((size_t)(N + 1) * 4);
    int*      fill   = (int*)     carve((size_t)N * 4);
    int*      partial= (int*)     carve(256 * 4);
    float*    meanp  = (float*)   carve(128 * 4);
    float*    rstdp  = (float*)   carve(128 * 4);
    float*    wsum   = (float*)   carve((size_t)N * 4);
    float*    a1     = (float*)   carve((size_t)N * 4);
    float*    dpart  = (float*)   carve((size_t)N * 4);

    const int nodeWaveBlocks = (N + 3) / 4;
    const int eBlocks = (E + 255) / 256;
    const int nBlocks = (N + 255) / 256;
    const int nb = (N + 1023) / 1024;
    const int wBlocks = (2 * 384 * 128 + 255) / 256;

    hipMemsetAsync(deg, 0, zeroBytes, stream);    // deg + stats

    // ---- CSR build + weight conversion ----
    hist_kernel<<<eBlocks, 256, 0, stream>>>(dstp, deg, E);
    scan_pass1<<<nb, 256, 0, stream>>>(deg, N, partial);
    scan_pass2<<<1, 256, 0, stream>>>(partial, nb);
    scan_pass3<<<nb, 256, 0, stream>>>(deg, N, partial, rowptr, fill, E);
    csr_fill_kernel<<<eBlocks, 256, 0, stream>>>(srcp, dstp, ew, fill, csr, E);
    wsum_csr_kernel<<<nBlocks, 256, 0, stream>>>(rowptr, csr, wsum, N);
    convert_weights_kernel<<<wBlocks, 256, 0, stream>>>(
        W1_in, W2_in, W3_in, Wt_in, W1_h, W2_h, W3_h, Wt_h);

    // ---- input standardization stats ----
    colstats_kernel<<<CS_BLOCKS, 256, 0, stream>>>(x, N, stats);
    finalize_stats_kernel<<<1, 128, 0, stream>>>(stats, N, meanp, rstdp);

    const int nTiles = (N + 63) / 64;
    const int gemmGrid = (nTiles < 512) ? nTiles : 512;

    // ---- layer 1 (standardize fused into GEMM staging) ----
    gemm_mfma_std_kernel<<<gemmGrid, 256, 0, stream>>>(
        x, meanp, rstdp, N, nTiles, Wt_in, b1_in, b3_in, wsum, buf_a, buf_d);
    aggregate_ln_kernel<<<nodeWaveBlocks, 256, 0, stream>>>(rowptr, csr, buf_a, buf_d, g1, beta1, buf_h, N);

    // ---- layers 2..3 ----
    for (int l = 0; l < 2; ++l) {
        gemm_mfma_kernel<<<gemmGrid, 256, 0, stream>>>(buf_h, N, nTiles, Wt_h, b1_h, b3_h, wsum, buf_a, buf_d);
        aggregate_ln_kernel<<<nodeWaveBlocks, 256, 0, stream>>>(rowptr, csr, buf_a, buf_d, g2, beta2, buf_h, N);
    }

    // ---- output layer ----
    out_gemv_kernel<<<nodeWaveBlocks, 256, 0, stream>>>(buf_h, N, W1_o, b1_o, W2_o, W3_o, b3_o, wsum, a1, dpart);
    gather_out_kernel<<<nBlocks, 256, 0, stream>>>(rowptr, csr, a1, dpart, (float*)d_out, N);
}

// Round 11
// 371.556 us; speedup vs baseline: 1.1378x; 1.0838x over previous
//
#include <hip/hip_runtime.h>
#include <hip/hip_bf16.h>
#include <math.h>

// ---------------------------------------------------------------------------
// GNN_72103910966081: 4-layer LEConv GNN, N=50000, E=600000, D=128.
// Round 11: revert to R8 structure (last known-good, 371us). Re-apply only:
// (1) merged weight convert (one launch); (2) colstats/reduce with 4-deep
// manual ILP (partials, no atomics) — R10 showed colstats 56us @260GB/s
// (one exposed load per loop iter). gemm_std fusion dropped (unproven suspect).
// ---------------------------------------------------------------------------

typedef _Float16 f16x8 __attribute__((ext_vector_type(8)));
typedef _Float16 f16x4 __attribute__((ext_vector_type(4)));
typedef float f32x4 __attribute__((ext_vector_type(4)));

#define LSTRIDE 136   // halves per LDS row: 128 + 8 (16B-aligned, breaks 2^k banks)

__device__ inline float wave_reduce_sum(float v) {
    #pragma unroll
    for (int off = 32; off > 0; off >>= 1)
        v += __shfl_xor(v, off, 64);
    return v;
}

// ===================== CSR build =====================

__global__ __launch_bounds__(256) void hist_kernel(
    const int* __restrict__ dst, int* __restrict__ deg, int E)
{
    int e = blockIdx.x * 256 + threadIdx.x;
    if (e < E) atomicAdd(&deg[dst[e]], 1);
}

__global__ __launch_bounds__(256) void scan_pass1(
    const int* __restrict__ deg, int N, int* __restrict__ partial)
{
    __shared__ int sh[256];
    int t = threadIdx.x;
    int base = blockIdx.x * 1024 + t * 4;
    int s = 0;
    #pragma unroll
    for (int i = 0; i < 4; ++i) { int idx = base + i; if (idx < N) s += deg[idx]; }
    sh[t] = s; __syncthreads();
    for (int off = 128; off > 0; off >>= 1) {
        if (t < off) sh[t] += sh[t + off];
        __syncthreads();
    }
    if (t == 0) partial[blockIdx.x] = sh[0];
}

__global__ __launch_bounds__(256) void scan_pass2(int* __restrict__ partial, int nb)
{
    __shared__ int sh[256];
    int t = threadIdx.x;
    sh[t] = (t < nb) ? partial[t] : 0;
    __syncthreads();
    for (int off = 1; off < 256; off <<= 1) {
        int x = sh[t];
        if (t >= off) x += sh[t - off];
        __syncthreads();
        sh[t] = x;
        __syncthreads();
    }
    if (t < nb) partial[t] = (t > 0) ? sh[t - 1] : 0;   // exclusive
}

__global__ __launch_bounds__(256) void scan_pass3(
    const int* __restrict__ deg, int N, const int* __restrict__ partial,
    int* __restrict__ rowptr, int* __restrict__ fill, int E)
{
    __shared__ int sh[256];
    int t = threadIdx.x;
    int base = blockIdx.x * 1024 + t * 4;
    int v[4]; int s = 0;
    #pragma unroll
    for (int i = 0; i < 4; ++i) { int idx = base + i; v[i] = (idx < N) ? deg[idx] : 0; s += v[i]; }
    sh[t] = s; __syncthreads();
    for (int off = 1; off < 256; off <<= 1) {
        int x = sh[t];
        if (t >= off) x += sh[t - off];
        __syncthreads();
        sh[t] = x;
        __syncthreads();
    }
    int off0 = partial[blockIdx.x] + ((t > 0) ? sh[t - 1] : 0);
    #pragma unroll
    for (int i = 0; i < 4; ++i) {
        int idx = base + i;
        if (idx < N) { rowptr[idx] = off0; fill[idx] = off0; off0 += v[i]; }
    }
    if (blockIdx.x == 0 && t == 0) rowptr[N] = E;
}

// single int atomic + 8B scatter (known-good R8 form)
__global__ __launch_bounds__(256) void csr_fill_kernel(
    const int* __restrict__ src, const int* __restrict__ dst,
    const float* __restrict__ ew, int* __restrict__ fill,
    int2* __restrict__ csr, int E)
{
    int e = blockIdx.x * 256 + threadIdx.x;
    if (e >= E) return;
    int d = dst[e];
    int pos = atomicAdd(&fill[d], 1);
    csr[pos] = make_int2(src[e], __float_as_int(ew[e]));
}

__global__ __launch_bounds__(256) void wsum_csr_kernel(
    const int* __restrict__ rowptr, const int2* __restrict__ csr,
    float* __restrict__ wsum, int N)
{
    int n = blockIdx.x * 256 + threadIdx.x;
    if (n >= N) return;
    int b = rowptr[n], en = rowptr[n + 1];
    float s = 0.f;
    for (int e = b; e < en; ++e) s += __int_as_float(csr[e].y);
    wsum[n] = s;
}

// ===================== weight convert+transpose (both sets, one launch) ====

__global__ __launch_bounds__(256) void convert_weights_kernel(
    const float* __restrict__ W1a, const float* __restrict__ W2a,
    const float* __restrict__ W3a, _Float16* __restrict__ Wta,
    const float* __restrict__ W1b, const float* __restrict__ W2b,
    const float* __restrict__ W3b, _Float16* __restrict__ Wtb)
{
    int idx = blockIdx.x * 256 + threadIdx.x;   // over 2*384*128
    if (idx >= 2 * 384 * 128) return;
    int set = idx >= 384 * 128;
    int id = idx - set * 384 * 128;
    int n = id >> 7, k = id & 127;
    const float* W = set ? ((n < 128) ? W1b : (n < 256) ? W2b : W3b)
                         : ((n < 128) ? W1a : (n < 256) ? W2a : W3a);
    _Float16* Wt = set ? Wtb : Wta;
    int c = n & 127;
    Wt[id] = (_Float16)W[k * 128 + c];
}

// ===================== input standardization (partials, 4-deep ILP) ========

#define CS_BLOCKS 512

__global__ __launch_bounds__(256) void colstats_kernel(
    const float* __restrict__ x, int N,
    float* __restrict__ ps, float* __restrict__ pss)   // [CS_BLOCKS][128] each
{
    __shared__ float shs[256][4];
    __shared__ float shq[256][4];
    int t = threadIdx.x;
    int g = t >> 5;
    int c = t & 31;
    const float4* xv = (const float4*)x;    // row stride 32
    const int S = CS_BLOCKS * 8;            // 4096 rows
    float s0=0.f,s1=0.f,s2=0.f,s3=0.f, q0=0.f,q1=0.f,q2=0.f,q3=0.f;
    int r = blockIdx.x * 8 + g;
    // 4 independent row-loads in flight per iteration
    for (; r + 3*S < N; r += 4*S) {
        float4 v0 = xv[(size_t)r * 32 + c];
        float4 v1 = xv[(size_t)(r + S) * 32 + c];
        float4 v2 = xv[(size_t)(r + 2*S) * 32 + c];
        float4 v3 = xv[(size_t)(r + 3*S) * 32 + c];
        s0 += v0.x + v1.x + v2.x + v3.x;
        s1 += v0.y + v1.y + v2.y + v3.y;
        s2 += v0.z + v1.z + v2.z + v3.z;
        s3 += v0.w + v1.w + v2.w + v3.w;
        q0 += v0.x*v0.x + v1.x*v1.x + v2.x*v2.x + v3.x*v3.x;
        q1 += v0.y*v0.y + v1.y*v1.y + v2.y*v2.y + v3.y*v3.y;
        q2 += v0.z*v0.z + v1.z*v1.z + v2.z*v2.z + v3.z*v3.z;
        q3 += v0.w*v0.w + v1.w*v1.w + v2.w*v2.w + v3.w*v3.w;
    }
    for (; r < N; r += S) {
        float4 v = xv[(size_t)r * 32 + c];
        s0 += v.x; s1 += v.y; s2 += v.z; s3 += v.w;
        q0 += v.x*v.x; q1 += v.y*v.y; q2 += v.z*v.z; q3 += v.w*v.w;
    }
    shs[t][0]=s0; shs[t][1]=s1; shs[t][2]=s2; shs[t][3]=s3;
    shq[t][0]=q0; shq[t][1]=q1; shq[t][2]=q2; shq[t][3]=q3;
    __syncthreads();
    if (t < 32) {
        float S4[4] = {0,0,0,0}, Q4[4] = {0,0,0,0};
        #pragma unroll
        for (int gg = 0; gg < 8; ++gg) {
            #pragma unroll
            for (int i = 0; i < 4; ++i) {
                S4[i] += shs[t + 32*gg][i];
                Q4[i] += shq[t + 32*gg][i];
            }
        }
        #pragma unroll
        for (int i = 0; i < 4; ++i) {
            ps [blockIdx.x * 128 + t*4 + i] = S4[i];
            pss[blockIdx.x * 128 + t*4 + i] = Q4[i];
        }
    }
}

__global__ __launch_bounds__(256) void reduce_stats_kernel(
    const float* __restrict__ ps, const float* __restrict__ pss, int N,
    float* __restrict__ mean, float* __restrict__ rstd)
{
    __shared__ float sh[256];
    int t = threadIdx.x;           // 256
    int f = t & 127;
    const float* src = (t >= 128) ? pss : ps;
    float s = 0.f;
    int r = 0;
    for (; r + 4 <= CS_BLOCKS; r += 4) {       // 4 loads in flight
        float a0 = src[(r    ) * 128 + f];
        float a1 = src[(r + 1) * 128 + f];
        float a2 = src[(r + 2) * 128 + f];
        float a3 = src[(r + 3) * 128 + f];
        s += (a0 + a1) + (a2 + a3);
    }
    for (; r < CS_BLOCKS; ++r) s += src[r * 128 + f];
    sh[t] = s;
    __syncthreads();
    if (t < 128) {
        float sum = sh[t], sumsq = sh[t + 128];
        float m = sum / (float)N;
        float var = (sumsq - sum * sum / (float)N) / (float)(N - 1);  // ddof=1
        var = fmaxf(var, 0.f);
        mean[t] = m;
        rstd[t] = 1.f / (sqrtf(var) + 1e-6f);
    }
}

__global__ __launch_bounds__(256) void standardize_kernel(
    const float* __restrict__ x, const float* __restrict__ mean,
    const float* __restrict__ rstd, _Float16* __restrict__ out, long long total)
{
    long long i = (long long)blockIdx.x * blockDim.x + threadIdx.x;
    if (i >= total) return;
    int f = (int)(i & 127);
    out[i] = (_Float16)((x[i] - mean[f]) * rstd[f]);
}

// ===================== MFMA fused GEMM (persistent, B in registers) ========

__global__ __launch_bounds__(256, 2) void gemm_mfma_kernel(
    const _Float16* __restrict__ h, int N, int nTiles,
    const _Float16* __restrict__ Wt,
    const float* __restrict__ b1,
    const float* __restrict__ b3,
    const float* __restrict__ wsum,
    _Float16* __restrict__ out_a, _Float16* __restrict__ out_d)
{
    __shared__ _Float16 ldsS[64 * LSTRIDE];
    __shared__ _Float16 lds_a[64 * LSTRIDE];
    __shared__ _Float16 lds_d[64 * LSTRIDE];

    int t = threadIdx.x;
    int wave = t >> 6;
    int lane = t & 63;
    int quad = lane >> 4;
    int c16  = lane & 15;

    const f16x8* wv = (const f16x8*)Wt;
    int ntl[6] = {2*wave, 2*wave+1, 8+2*wave, 9+2*wave, 16+2*wave, 17+2*wave};
    f16x8 bfrag[6][4];
    #pragma unroll
    for (int j = 0; j < 6; ++j) {
        int nrow = ntl[j] * 16 + c16;
        #pragma unroll
        for (int s = 0; s < 4; ++s)
            bfrag[j][s] = wv[(size_t)nrow * 16 + s * 4 + quad];
    }
    float bb1[2], bb3[2];
    #pragma unroll
    for (int j = 0; j < 2; ++j) {
        int col = (2*wave + j) * 16 + c16;
        bb1[j] = b1[col];
        bb3[j] = b3[col];
    }

    const f16x8* hv = (const f16x8*)h;
    f16x8* oa = (f16x8*)out_a;
    f16x8* od = (f16x8*)out_d;

    for (int tile = blockIdx.x; tile < nTiles; tile += gridDim.x) {
        int row0 = tile * 64;

        #pragma unroll
        for (int i = 0; i < 4; ++i) {
            int idx = i * 256 + t;
            int row = idx >> 4;
            int chunk = idx & 15;
            int grow = row0 + row;
            if (grow >= N) grow = N - 1;
            *(f16x8*)&ldsS[row * LSTRIDE + chunk * 8] = hv[(size_t)grow * 16 + chunk];
        }
        __syncthreads();

        #pragma unroll
        for (int r = 0; r < 4; ++r) {
            f16x8 afrag[4];
            #pragma unroll
            for (int s = 0; s < 4; ++s)
                afrag[s] = *(const f16x8*)&ldsS[(r*16 + c16) * LSTRIDE + (s*4 + quad) * 8];

            f32x4 acc[6];
            #pragma unroll
            for (int j = 0; j < 6; ++j) acc[j] = (f32x4){0.f, 0.f, 0.f, 0.f};
            #pragma unroll
            for (int s = 0; s < 4; ++s) {
                #pragma unroll
                for (int j = 0; j < 6; ++j)
                    acc[j] = __builtin_amdgcn_mfma_f32_16x16x32_f16(afrag[s], bfrag[j][s], acc[j], 0, 0, 0);
            }

            float wsv[4];
            #pragma unroll
            for (int reg = 0; reg < 4; ++reg) {
                int gr = row0 + r*16 + quad*4 + reg;
                wsv[reg] = wsum[(gr < N) ? gr : (N - 1)];
            }
            #pragma unroll
            for (int j = 0; j < 2; ++j) {
                int col = (2*wave + j) * 16 + c16;
                #pragma unroll
                for (int reg = 0; reg < 4; ++reg) {
                    int lr = r*16 + quad*4 + reg;
                    lds_a[lr * LSTRIDE + col] = (_Float16)(acc[j][reg] + bb1[j]);
                    lds_d[lr * LSTRIDE + col] =
                        (_Float16)(acc[4+j][reg] + bb3[j] - wsv[reg] * acc[2+j][reg]);
                }
            }
        }
        __syncthreads();

        #pragma unroll
        for (int i = 0; i < 4; ++i) {
            int idx = i * 256 + t;
            int row = idx >> 4;
            int c8  = idx & 15;
            int grow = row0 + row;
            if (grow < N) {
                f16x8 va = *(const f16x8*)&lds_a[row * LSTRIDE + c8 * 8];
                oa[(size_t)grow * 16 + c8] = va;
                f16x8 vd = *(const f16x8*)&lds_d[row * LSTRIDE + c8 * 8];
                od[(size_t)grow * 16 + c8] = vd;
            }
        }
        __syncthreads();
    }
}

// ===================== fused gather + LN + leaky =====================
// 1 node per wave; 4 edge-groups x 16 lanes x f16x8 (16B/lane).

__global__ __launch_bounds__(256) void aggregate_ln_kernel(
    const int* __restrict__ rowptr, const int2* __restrict__ csr,
    const _Float16* __restrict__ a, const _Float16* __restrict__ d,
    const float* __restrict__ g, const float* __restrict__ beta,
    _Float16* __restrict__ out, int N)
{
    int wave = threadIdx.x >> 6;
    int lane = threadIdx.x & 63;
    int grp  = lane >> 4;        // 0..3: edge group
    int l    = lane & 15;        // feature chunk: cols 8l..8l+7
    int node = blockIdx.x * 4 + wave;
    if (node >= N) return;
    int b = rowptr[node], en = rowptr[node + 1];
    int deg = en - b;

    const f16x8* av = (const f16x8*)a;   // row stride 16 chunks
    float acc[8] = {0,0,0,0,0,0,0,0};

    int nk = (deg + 3) >> 2;             // edge e = b + k*4 + grp
    int k = 0;
    for (; k + 4 <= nk; k += 4) {        // 16 edge-rows in flight
        int2 p[4];
        #pragma unroll
        for (int j = 0; j < 4; ++j) {
            int idx = b + (k + j) * 4 + grp;
            int idc = (idx < en) ? idx : b;
            p[j] = csr[idc];
            if (idx >= en) p[j].y = 0;
        }
        f16x8 v[4];
        #pragma unroll
        for (int j = 0; j < 4; ++j)
            v[j] = av[(size_t)p[j].x * 16 + l];
        #pragma unroll
        for (int j = 0; j < 4; ++j) {
            float w = __int_as_float(p[j].y);
            #pragma unroll
            for (int i = 0; i < 8; ++i) acc[i] += w * (float)v[j][i];
        }
    }
    for (; k < nk; ++k) {
        int idx = b + k * 4 + grp;
        int idc = (idx < en) ? idx : b;
        int2 p = csr[idc];
        if (idx >= en) p.y = 0;
        f16x8 v = av[(size_t)p.x * 16 + l];
        float w = __int_as_float(p.y);
        #pragma unroll
        for (int i = 0; i < 8; ++i) acc[i] += w * (float)v[i];
    }

    #pragma unroll
    for (int i = 0; i < 8; ++i) {
        acc[i] += __shfl_xor(acc[i], 16, 64);
        acc[i] += __shfl_xor(acc[i], 32, 64);
    }

    f16x8 dv = ((const f16x8*)d)[(size_t)node * 16 + l];
    float v[8];
    float s = 0.f, ss = 0.f;
    #pragma unroll
    for (int i = 0; i < 8; ++i) {
        v[i] = acc[i] + (float)dv[i];
        s += v[i]; ss += v[i] * v[i];
    }
    #pragma unroll
    for (int off = 1; off <= 8; off <<= 1) {
        s  += __shfl_xor(s,  off, 64);
        ss += __shfl_xor(ss, off, 64);
    }
    float mean = s * (1.f / 128.f);
    float var = ss * (1.f / 128.f) - mean * mean;
    float rstd = rsqrtf(var + 1e-5f);

    const float4* gv4 = (const float4*)g;
    const float4* bv4 = (const float4*)beta;
    float4 ga = gv4[l*2], gb = gv4[l*2+1];
    float4 ba = bv4[l*2], bb = bv4[l*2+1];
    float go[8] = {ga.x,ga.y,ga.z,ga.w,gb.x,gb.y,gb.z,gb.w};
    float bo[8] = {ba.x,ba.y,ba.z,ba.w,bb.x,bb.y,bb.z,bb.w};
    f16x8 ov;
    #pragma unroll
    for (int i = 0; i < 8; ++i) {
        float o = (v[i] - mean) * rstd * go[i] + bo[i];
        o = o >= 0.f ? o : 0.1f * o;
        ov[i] = (_Float16)o;
    }
    if (grp == 0)
        ((f16x8*)out)[(size_t)node * 16 + l] = ov;
}

// ===================== output layer (D_OUT=1) =====================

__global__ __launch_bounds__(256) void out_gemv_kernel(
    const _Float16* __restrict__ h, int N,
    const float* __restrict__ W1, const float* __restrict__ b1,
    const float* __restrict__ W2,
    const float* __restrict__ W3, const float* __restrict__ b3,
    const float* __restrict__ wsum,
    float* __restrict__ a1, float* __restrict__ dpart)
{
    int wave = threadIdx.x >> 6;
    int lane = threadIdx.x & 63;
    int node = blockIdx.x * 4 + wave;
    if (node >= N) return;
    const _Float16* row = h + (size_t)node * 128;
    float h0 = (float)row[lane], h1 = (float)row[lane + 64];
    float s1 = wave_reduce_sum(h0 * W1[lane] + h1 * W1[lane + 64]);
    float s2 = wave_reduce_sum(h0 * W2[lane] + h1 * W2[lane + 64]);
    float s3 = wave_reduce_sum(h0 * W3[lane] + h1 * W3[lane + 64]);
    if (lane == 0) {
        a1[node] = s1 + b1[0];
        dpart[node] = s3 + b3[0] - wsum[node] * s2;
    }
}

__global__ __launch_bounds__(256) void gather_out_kernel(
    const int* __restrict__ rowptr, const int2* __restrict__ csr,
    const float* __restrict__ a1, const float* __restrict__ dpart,
    float* __restrict__ out, int N)
{
    int n = blockIdx.x * 256 + threadIdx.x;
    if (n >= N) return;
    int b = rowptr[n], en = rowptr[n + 1];
    float s = dpart[n];
    int e = b;
    for (; e + 4 <= en; e += 4) {
        int2 p0 = csr[e], p1 = csr[e+1], p2 = csr[e+2], p3 = csr[e+3];
        float x0 = a1[p0.x], x1 = a1[p1.x], x2 = a1[p2.x], x3 = a1[p3.x];
        s += __int_as_float(p0.y) * x0 + __int_as_float(p1.y) * x1
           + __int_as_float(p2.y) * x2 + __int_as_float(p3.y) * x3;
    }
    for (; e < en; ++e) {
        int2 p = csr[e];
        s += __int_as_float(p.y) * a1[p.x];
    }
    out[n] = 1.f / (1.f + expf(-s));
}

// ---------------------------------------------------------------------------
extern "C" void kernel_launch(void* const* d_in, const int* in_sizes, int n_in,
                              void* d_out, int out_size, void* d_ws, size_t ws_size,
                              hipStream_t stream)
{
    const float* x     = (const float*)d_in[0];
    const float* ew    = (const float*)d_in[1];
    const float* W1_in = (const float*)d_in[2];
    const float* b1_in = (const float*)d_in[3];
    const float* W2_in = (const float*)d_in[4];
    const float* W3_in = (const float*)d_in[5];
    const float* b3_in = (const float*)d_in[6];
    const float* W1_h  = (const float*)d_in[7];
    const float* b1_h  = (const float*)d_in[8];
    const float* W2_h  = (const float*)d_in[9];
    const float* W3_h  = (const float*)d_in[10];
    const float* b3_h  = (const float*)d_in[11];
    const float* W1_o  = (const float*)d_in[12];
    const float* b1_o  = (const float*)d_in[13];
    const float* W2_o  = (const float*)d_in[14];
    const float* W3_o  = (const float*)d_in[15];
    const float* b3_o  = (const float*)d_in[16];
    const float* g1    = (const float*)d_in[17];
    const float* beta1 = (const float*)d_in[18];
    const float* g2    = (const float*)d_in[19];
    const float* beta2 = (const float*)d_in[20];
    const int*   eidx  = (const int*)d_in[21];

    const int N = in_sizes[0] / 128;
    const int E = in_sizes[1];
    const int* srcp = eidx;
    const int* dstp = eidx + E;

    // ---- workspace carve-out (256B-aligned chunks) ----
    size_t off = 0;
    auto carve = [&](size_t nbytes) -> void* {
        void* p = (char*)d_ws + off;
        off += (nbytes + 255) & ~(size_t)255;
        return p;
    };
    int*      deg    = (int*)     carve((size_t)N * 4);
    size_t zeroBytes = off;                       // only deg needs zeroing
    _Float16* buf_h  = (_Float16*)carve((size_t)N * 128 * 2);
    _Float16* buf_a  = (_Float16*)carve((size_t)N * 128 * 2);
    _Float16* buf_d  = (_Float16*)carve((size_t)N * 128 * 2);
    int2*     csr    = (int2*)    carve((size_t)E * 8);
    _Float16* Wt_in  = (_Float16*)carve(384 * 128 * 2);
    _Float16* Wt_h   = (_Float16*)carve(384 * 128 * 2);
    int*      rowptr = (int*)     carve((size_t)(N + 1) * 4);
    int*      fill   = (int*)     carve((size_t)N * 4);
    int*      partial= (int*)     carve(256 * 4);
    float*    ps     = (float*)   carve((size_t)CS_BLOCKS * 128 * 4);
    float*    pss    = (float*)   carve((size_t)CS_BLOCKS * 128 * 4);
    float*    meanp  = (float*)   carve(128 * 4);
    float*    rstdp  = (float*)   carve(128 * 4);
    float*    wsum   = (float*)   carve((size_t)N * 4);
    float*    a1     = (float*)   carve((size_t)N * 4);
    float*    dpart  = (float*)   carve((size_t)N * 4);

    const long long totNF = (long long)N * 128;
    const int nodeWaveBlocks = (N + 3) / 4;
    const int eBlocks = (E + 255) / 256;
    const int nBlocks = (N + 255) / 256;
    const int nb = (N + 1023) / 1024;
    const int wBlocks = (2 * 384 * 128 + 255) / 256;

    hipMemsetAsync(deg, 0, zeroBytes, stream);

    // ---- CSR build + weight conversion ----
    hist_kernel<<<eBlocks, 256, 0, stream>>>(dstp, deg, E);
    scan_pass1<<<nb, 256, 0, stream>>>(deg, N, partial);
    scan_pass2<<<1, 256, 0, stream>>>(partial, nb);
    scan_pass3<<<nb, 256, 0, stream>>>(deg, N, partial, rowptr, fill, E);
    csr_fill_kernel<<<eBlocks, 256, 0, stream>>>(srcp, dstp, ew, fill, csr, E);
    wsum_csr_kernel<<<nBlocks, 256, 0, stream>>>(rowptr, csr, wsum, N);
    convert_weights_kernel<<<wBlocks, 256, 0, stream>>>(
        W1_in, W2_in, W3_in, Wt_in, W1_h, W2_h, W3_h, Wt_h);

    // ---- input standardization ----
    colstats_kernel<<<CS_BLOCKS, 256, 0, stream>>>(x, N, ps, pss);
    reduce_stats_kernel<<<1, 256, 0, stream>>>(ps, pss, N, meanp, rstdp);
    standardize_kernel<<<(int)((totNF + 255) / 256), 256, 0, stream>>>(x, meanp, rstdp, buf_h, totNF);

    const int nTiles = (N + 63) / 64;
    const int gemmGrid = (nTiles < 512) ? nTiles : 512;

    // ---- layer 1 ----
    gemm_mfma_kernel<<<gemmGrid, 256, 0, stream>>>(buf_h, N, nTiles, Wt_in, b1_in, b3_in, wsum, buf_a, buf_d);
    aggregate_ln_kernel<<<nodeWaveBlocks, 256, 0, stream>>>(rowptr, csr, buf_a, buf_d, g1, beta1, buf_h, N);

    // ---- layers 2..3 ----
    for (int l = 0; l < 2; ++l) {
        gemm_mfma_kernel<<<gemmGrid, 256, 0, stream>>>(buf_h, N, nTiles, Wt_h, b1_h, b3_h, wsum, buf_a, buf_d);
        aggregate_ln_kernel<<<nodeWaveBlocks, 256, 0, stream>>>(rowptr, csr, buf_a, buf_d, g2, beta2, buf_h, N);
    }

    // ---- output layer ----
    out_gemv_kernel<<<nodeWaveBlocks, 256, 0, stream>>>(buf_h, N, W1_o, b1_o, W2_o, W3_o, b3_o, wsum, a1, dpart);
    gather_out_kernel<<<nBlocks, 256, 0, stream>>>(rowptr, csr, a1, dpart, (float*)d_out, N);
}

// Round 12
// 337.730 us; speedup vs baseline: 1.2517x; 1.1002x over previous
//
#include <hip/hip_runtime.h>
#include <hip/hip_bf16.h>
#include <math.h>

// ---------------------------------------------------------------------------
// GNN_72103910966081: 4-layer LEConv GNN, N=50000, E=600000, D=128.
// Round 12: (1) rank-based CSR fill — hist's atomicAdd return value IS the
// within-row rank, so csr_fill needs no atomics (R9-R11 ledger: fill atomics
// cost ~12-40us); (2) re-apply gemm_std fusion (standardize folded into
// layer-1 GEMM staging — R9-verified, never implicated in the regression).
// ---------------------------------------------------------------------------

typedef _Float16 f16x8 __attribute__((ext_vector_type(8)));
typedef _Float16 f16x4 __attribute__((ext_vector_type(4)));
typedef float f32x4 __attribute__((ext_vector_type(4)));

#define LSTRIDE 136   // halves per LDS row: 128 + 8 (16B-aligned, breaks 2^k banks)

__device__ inline float wave_reduce_sum(float v) {
    #pragma unroll
    for (int off = 32; off > 0; off >>= 1)
        v += __shfl_xor(v, off, 64);
    return v;
}

// ===================== CSR build =====================

// histogram + per-edge within-row rank (atomicAdd return value)
__global__ __launch_bounds__(256) void hist_kernel(
    const int* __restrict__ dst, int* __restrict__ deg,
    int* __restrict__ rank, int E)
{
    int e = blockIdx.x * 256 + threadIdx.x;
    if (e < E) rank[e] = atomicAdd(&deg[dst[e]], 1);
}

__global__ __launch_bounds__(256) void scan_pass1(
    const int* __restrict__ deg, int N, int* __restrict__ partial)
{
    __shared__ int sh[256];
    int t = threadIdx.x;
    int base = blockIdx.x * 1024 + t * 4;
    int s = 0;
    #pragma unroll
    for (int i = 0; i < 4; ++i) { int idx = base + i; if (idx < N) s += deg[idx]; }
    sh[t] = s; __syncthreads();
    for (int off = 128; off > 0; off >>= 1) {
        if (t < off) sh[t] += sh[t + off];
        __syncthreads();
    }
    if (t == 0) partial[blockIdx.x] = sh[0];
}

__global__ __launch_bounds__(256) void scan_pass2(int* __restrict__ partial, int nb)
{
    __shared__ int sh[256];
    int t = threadIdx.x;
    sh[t] = (t < nb) ? partial[t] : 0;
    __syncthreads();
    for (int off = 1; off < 256; off <<= 1) {
        int x = sh[t];
        if (t >= off) x += sh[t - off];
        __syncthreads();
        sh[t] = x;
        __syncthreads();
    }
    if (t < nb) partial[t] = (t > 0) ? sh[t - 1] : 0;   // exclusive
}

__global__ __launch_bounds__(256) void scan_pass3(
    const int* __restrict__ deg, int N, const int* __restrict__ partial,
    int* __restrict__ rowptr, int E)
{
    __shared__ int sh[256];
    int t = threadIdx.x;
    int base = blockIdx.x * 1024 + t * 4;
    int v[4]; int s = 0;
    #pragma unroll
    for (int i = 0; i < 4; ++i) { int idx = base + i; v[i] = (idx < N) ? deg[idx] : 0; s += v[i]; }
    sh[t] = s; __syncthreads();
    for (int off = 1; off < 256; off <<= 1) {
        int x = sh[t];
        if (t >= off) x += sh[t - off];
        __syncthreads();
        sh[t] = x;
        __syncthreads();
    }
    int off0 = partial[blockIdx.x] + ((t > 0) ? sh[t - 1] : 0);
    #pragma unroll
    for (int i = 0; i < 4; ++i) {
        int idx = base + i;
        if (idx < N) { rowptr[idx] = off0; off0 += v[i]; }
    }
    if (blockIdx.x == 0 && t == 0) rowptr[N] = E;
}

// NO atomics: pos = rowptr[dst] + rank (rank captured in hist)
__global__ __launch_bounds__(256) void csr_fill_kernel(
    const int* __restrict__ src, const int* __restrict__ dst,
    const float* __restrict__ ew, const int* __restrict__ rowptr,
    const int* __restrict__ rank, int2* __restrict__ csr, int E)
{
    int e = blockIdx.x * 256 + threadIdx.x;
    if (e >= E) return;
    int d = dst[e];
    int pos = rowptr[d] + rank[e];
    csr[pos] = make_int2(src[e], __float_as_int(ew[e]));
}

__global__ __launch_bounds__(256) void wsum_csr_kernel(
    const int* __restrict__ rowptr, const int2* __restrict__ csr,
    float* __restrict__ wsum, int N)
{
    int n = blockIdx.x * 256 + threadIdx.x;
    if (n >= N) return;
    int b = rowptr[n], en = rowptr[n + 1];
    float s = 0.f;
    for (int e = b; e < en; ++e) s += __int_as_float(csr[e].y);
    wsum[n] = s;
}

// ===================== weight convert+transpose (both sets, one launch) ====

__global__ __launch_bounds__(256) void convert_weights_kernel(
    const float* __restrict__ W1a, const float* __restrict__ W2a,
    const float* __restrict__ W3a, _Float16* __restrict__ Wta,
    const float* __restrict__ W1b, const float* __restrict__ W2b,
    const float* __restrict__ W3b, _Float16* __restrict__ Wtb)
{
    int idx = blockIdx.x * 256 + threadIdx.x;   // over 2*384*128
    if (idx >= 2 * 384 * 128) return;
    int set = idx >= 384 * 128;
    int id = idx - set * 384 * 128;
    int n = id >> 7, k = id & 127;
    const float* W = set ? ((n < 128) ? W1b : (n < 256) ? W2b : W3b)
                         : ((n < 128) ? W1a : (n < 256) ? W2a : W3a);
    _Float16* Wt = set ? Wtb : Wta;
    int c = n & 127;
    Wt[id] = (_Float16)W[k * 128 + c];
}

// ===================== input standardization (partials, 4-deep ILP) ========

#define CS_BLOCKS 512

__global__ __launch_bounds__(256) void colstats_kernel(
    const float* __restrict__ x, int N,
    float* __restrict__ ps, float* __restrict__ pss)   // [CS_BLOCKS][128] each
{
    __shared__ float shs[256][4];
    __shared__ float shq[256][4];
    int t = threadIdx.x;
    int g = t >> 5;
    int c = t & 31;
    const float4* xv = (const float4*)x;    // row stride 32
    const int S = CS_BLOCKS * 8;            // 4096 rows
    float s0=0.f,s1=0.f,s2=0.f,s3=0.f, q0=0.f,q1=0.f,q2=0.f,q3=0.f;
    int r = blockIdx.x * 8 + g;
    for (; r + 3*S < N; r += 4*S) {
        float4 v0 = xv[(size_t)r * 32 + c];
        float4 v1 = xv[(size_t)(r + S) * 32 + c];
        float4 v2 = xv[(size_t)(r + 2*S) * 32 + c];
        float4 v3 = xv[(size_t)(r + 3*S) * 32 + c];
        s0 += v0.x + v1.x + v2.x + v3.x;
        s1 += v0.y + v1.y + v2.y + v3.y;
        s2 += v0.z + v1.z + v2.z + v3.z;
        s3 += v0.w + v1.w + v2.w + v3.w;
        q0 += v0.x*v0.x + v1.x*v1.x + v2.x*v2.x + v3.x*v3.x;
        q1 += v0.y*v0.y + v1.y*v1.y + v2.y*v2.y + v3.y*v3.y;
        q2 += v0.z*v0.z + v1.z*v1.z + v2.z*v2.z + v3.z*v3.z;
        q3 += v0.w*v0.w + v1.w*v1.w + v2.w*v2.w + v3.w*v3.w;
    }
    for (; r < N; r += S) {
        float4 v = xv[(size_t)r * 32 + c];
        s0 += v.x; s1 += v.y; s2 += v.z; s3 += v.w;
        q0 += v.x*v.x; q1 += v.y*v.y; q2 += v.z*v.z; q3 += v.w*v.w;
    }
    shs[t][0]=s0; shs[t][1]=s1; shs[t][2]=s2; shs[t][3]=s3;
    shq[t][0]=q0; shq[t][1]=q1; shq[t][2]=q2; shq[t][3]=q3;
    __syncthreads();
    if (t < 32) {
        float S4[4] = {0,0,0,0}, Q4[4] = {0,0,0,0};
        #pragma unroll
        for (int gg = 0; gg < 8; ++gg) {
            #pragma unroll
            for (int i = 0; i < 4; ++i) {
                S4[i] += shs[t + 32*gg][i];
                Q4[i] += shq[t + 32*gg][i];
            }
        }
        #pragma unroll
        for (int i = 0; i < 4; ++i) {
            ps [blockIdx.x * 128 + t*4 + i] = S4[i];
            pss[blockIdx.x * 128 + t*4 + i] = Q4[i];
        }
    }
}

__global__ __launch_bounds__(256) void reduce_stats_kernel(
    const float* __restrict__ ps, const float* __restrict__ pss, int N,
    float* __restrict__ mean, float* __restrict__ rstd)
{
    __shared__ float sh[256];
    int t = threadIdx.x;           // 256
    int f = t & 127;
    const float* src = (t >= 128) ? pss : ps;
    float s = 0.f;
    int r = 0;
    for (; r + 4 <= CS_BLOCKS; r += 4) {
        float a0 = src[(r    ) * 128 + f];
        float a1 = src[(r + 1) * 128 + f];
        float a2 = src[(r + 2) * 128 + f];
        float a3 = src[(r + 3) * 128 + f];
        s += (a0 + a1) + (a2 + a3);
    }
    for (; r < CS_BLOCKS; ++r) s += src[r * 128 + f];
    sh[t] = s;
    __syncthreads();
    if (t < 128) {
        float sum = sh[t], sumsq = sh[t + 128];
        float m = sum / (float)N;
        float var = (sumsq - sum * sum / (float)N) / (float)(N - 1);  // ddof=1
        var = fmaxf(var, 0.f);
        mean[t] = m;
        rstd[t] = 1.f / (sqrtf(var) + 1e-6f);
    }
}

// ===================== MFMA fused GEMM (persistent, B in registers) ========
// Variant 1: reads fp16 h (layers 2..3).

__global__ __launch_bounds__(256, 2) void gemm_mfma_kernel(
    const _Float16* __restrict__ h, int N, int nTiles,
    const _Float16* __restrict__ Wt,
    const float* __restrict__ b1,
    const float* __restrict__ b3,
    const float* __restrict__ wsum,
    _Float16* __restrict__ out_a, _Float16* __restrict__ out_d)
{
    __shared__ _Float16 ldsS[64 * LSTRIDE];
    __shared__ _Float16 lds_a[64 * LSTRIDE];
    __shared__ _Float16 lds_d[64 * LSTRIDE];

    int t = threadIdx.x;
    int wave = t >> 6;
    int lane = t & 63;
    int quad = lane >> 4;
    int c16  = lane & 15;

    const f16x8* wv = (const f16x8*)Wt;
    int ntl[6] = {2*wave, 2*wave+1, 8+2*wave, 9+2*wave, 16+2*wave, 17+2*wave};
    f16x8 bfrag[6][4];
    #pragma unroll
    for (int j = 0; j < 6; ++j) {
        int nrow = ntl[j] * 16 + c16;
        #pragma unroll
        for (int s = 0; s < 4; ++s)
            bfrag[j][s] = wv[(size_t)nrow * 16 + s * 4 + quad];
    }
    float bb1[2], bb3[2];
    #pragma unroll
    for (int j = 0; j < 2; ++j) {
        int col = (2*wave + j) * 16 + c16;
        bb1[j] = b1[col];
        bb3[j] = b3[col];
    }

    const f16x8* hv = (const f16x8*)h;
    f16x8* oa = (f16x8*)out_a;
    f16x8* od = (f16x8*)out_d;

    for (int tile = blockIdx.x; tile < nTiles; tile += gridDim.x) {
        int row0 = tile * 64;

        #pragma unroll
        for (int i = 0; i < 4; ++i) {
            int idx = i * 256 + t;
            int row = idx >> 4;
            int chunk = idx & 15;
            int grow = row0 + row;
            if (grow >= N) grow = N - 1;
            *(f16x8*)&ldsS[row * LSTRIDE + chunk * 8] = hv[(size_t)grow * 16 + chunk];
        }
        __syncthreads();

        #pragma unroll
        for (int r = 0; r < 4; ++r) {
            f16x8 afrag[4];
            #pragma unroll
            for (int s = 0; s < 4; ++s)
                afrag[s] = *(const f16x8*)&ldsS[(r*16 + c16) * LSTRIDE + (s*4 + quad) * 8];

            f32x4 acc[6];
            #pragma unroll
            for (int j = 0; j < 6; ++j) acc[j] = (f32x4){0.f, 0.f, 0.f, 0.f};
            #pragma unroll
            for (int s = 0; s < 4; ++s) {
                #pragma unroll
                for (int j = 0; j < 6; ++j)
                    acc[j] = __builtin_amdgcn_mfma_f32_16x16x32_f16(afrag[s], bfrag[j][s], acc[j], 0, 0, 0);
            }

            float wsv[4];
            #pragma unroll
            for (int reg = 0; reg < 4; ++reg) {
                int gr = row0 + r*16 + quad*4 + reg;
                wsv[reg] = wsum[(gr < N) ? gr : (N - 1)];
            }
            #pragma unroll
            for (int j = 0; j < 2; ++j) {
                int col = (2*wave + j) * 16 + c16;
                #pragma unroll
                for (int reg = 0; reg < 4; ++reg) {
                    int lr = r*16 + quad*4 + reg;
                    lds_a[lr * LSTRIDE + col] = (_Float16)(acc[j][reg] + bb1[j]);
                    lds_d[lr * LSTRIDE + col] =
                        (_Float16)(acc[4+j][reg] + bb3[j] - wsv[reg] * acc[2+j][reg]);
                }
            }
        }
        __syncthreads();

        #pragma unroll
        for (int i = 0; i < 4; ++i) {
            int idx = i * 256 + t;
            int row = idx >> 4;
            int c8  = idx & 15;
            int grow = row0 + row;
            if (grow < N) {
                f16x8 va = *(const f16x8*)&lds_a[row * LSTRIDE + c8 * 8];
                oa[(size_t)grow * 16 + c8] = va;
                f16x8 vd = *(const f16x8*)&lds_d[row * LSTRIDE + c8 * 8];
                od[(size_t)grow * 16 + c8] = vd;
            }
        }
        __syncthreads();
    }
}

// Variant 2 (layer 1): reads fp32 x, fuses standardization into staging.

__global__ __launch_bounds__(256, 2) void gemm_mfma_std_kernel(
    const float* __restrict__ x,
    const float* __restrict__ meanp, const float* __restrict__ rstdp,
    int N, int nTiles,
    const _Float16* __restrict__ Wt,
    const float* __restrict__ b1,
    const float* __restrict__ b3,
    const float* __restrict__ wsum,
    _Float16* __restrict__ out_a, _Float16* __restrict__ out_d)
{
    __shared__ _Float16 ldsS[64 * LSTRIDE];
    __shared__ _Float16 lds_a[64 * LSTRIDE];
    __shared__ _Float16 lds_d[64 * LSTRIDE];

    int t = threadIdx.x;
    int wave = t >> 6;
    int lane = t & 63;
    int quad = lane >> 4;
    int c16  = lane & 15;

    const f16x8* wv = (const f16x8*)Wt;
    int ntl[6] = {2*wave, 2*wave+1, 8+2*wave, 9+2*wave, 16+2*wave, 17+2*wave};
    f16x8 bfrag[6][4];
    #pragma unroll
    for (int j = 0; j < 6; ++j) {
        int nrow = ntl[j] * 16 + c16;
        #pragma unroll
        for (int s = 0; s < 4; ++s)
            bfrag[j][s] = wv[(size_t)nrow * 16 + s * 4 + quad];
    }
    float bb1[2], bb3[2];
    #pragma unroll
    for (int j = 0; j < 2; ++j) {
        int col = (2*wave + j) * 16 + c16;
        bb1[j] = b1[col];
        bb3[j] = b3[col];
    }

    int c4 = t & 31;
    float4 mu = ((const float4*)meanp)[c4];
    float4 rs = ((const float4*)rstdp)[c4];

    const float4* xv = (const float4*)x;   // row stride 32 float4
    f16x8* oa = (f16x8*)out_a;
    f16x8* od = (f16x8*)out_d;

    for (int tile = blockIdx.x; tile < nTiles; tile += gridDim.x) {
        int row0 = tile * 64;

        #pragma unroll
        for (int i = 0; i < 8; ++i) {
            int idx = i * 256 + t;        // 0..2047
            int row = idx >> 5;           // 0..63
            int grow = row0 + row;
            if (grow >= N) grow = N - 1;
            float4 v = xv[(size_t)grow * 32 + c4];
            f16x4 o;
            o.x = (_Float16)((v.x - mu.x) * rs.x);
            o.y = (_Float16)((v.y - mu.y) * rs.y);
            o.z = (_Float16)((v.z - mu.z) * rs.z);
            o.w = (_Float16)((v.w - mu.w) * rs.w);
            *(f16x4*)&ldsS[row * LSTRIDE + c4 * 4] = o;
        }
        __syncthreads();

        #pragma unroll
        for (int r = 0; r < 4; ++r) {
            f16x8 afrag[4];
            #pragma unroll
            for (int s = 0; s < 4; ++s)
                afrag[s] = *(const f16x8*)&ldsS[(r*16 + c16) * LSTRIDE + (s*4 + quad) * 8];

            f32x4 acc[6];
            #pragma unroll
            for (int j = 0; j < 6; ++j) acc[j] = (f32x4){0.f, 0.f, 0.f, 0.f};
            #pragma unroll
            for (int s = 0; s < 4; ++s) {
                #pragma unroll
                for (int j = 0; j < 6; ++j)
                    acc[j] = __builtin_amdgcn_mfma_f32_16x16x32_f16(afrag[s], bfrag[j][s], acc[j], 0, 0, 0);
            }

            float wsv[4];
            #pragma unroll
            for (int reg = 0; reg < 4; ++reg) {
                int gr = row0 + r*16 + quad*4 + reg;
                wsv[reg] = wsum[(gr < N) ? gr : (N - 1)];
            }
            #pragma unroll
            for (int j = 0; j < 2; ++j) {
                int col = (2*wave + j) * 16 + c16;
                #pragma unroll
                for (int reg = 0; reg < 4; ++reg) {
                    int lr = r*16 + quad*4 + reg;
                    lds_a[lr * LSTRIDE + col] = (_Float16)(acc[j][reg] + bb1[j]);
                    lds_d[lr * LSTRIDE + col] =
                        (_Float16)(acc[4+j][reg] + bb3[j] - wsv[reg] * acc[2+j][reg]);
                }
            }
        }
        __syncthreads();

        #pragma unroll
        for (int i = 0; i < 4; ++i) {
            int idx = i * 256 + t;
            int row = idx >> 4;
            int c8  = idx & 15;
            int grow = row0 + row;
            if (grow < N) {
                f16x8 va = *(const f16x8*)&lds_a[row * LSTRIDE + c8 * 8];
                oa[(size_t)grow * 16 + c8] = va;
                f16x8 vd = *(const f16x8*)&lds_d[row * LSTRIDE + c8 * 8];
                od[(size_t)grow * 16 + c8] = vd;
            }
        }
        __syncthreads();
    }
}

// ===================== fused gather + LN + leaky =====================
// 1 node per wave; 4 edge-groups x 16 lanes x f16x8 (16B/lane).

__global__ __launch_bounds__(256) void aggregate_ln_kernel(
    const int* __restrict__ rowptr, const int2* __restrict__ csr,
    const _Float16* __restrict__ a, const _Float16* __restrict__ d,
    const float* __restrict__ g, const float* __restrict__ beta,
    _Float16* __restrict__ out, int N)
{
    int wave = threadIdx.x >> 6;
    int lane = threadIdx.x & 63;
    int grp  = lane >> 4;        // 0..3: edge group
    int l    = lane & 15;        // feature chunk: cols 8l..8l+7
    int node = blockIdx.x * 4 + wave;
    if (node >= N) return;
    int b = rowptr[node], en = rowptr[node + 1];
    int deg = en - b;

    const f16x8* av = (const f16x8*)a;   // row stride 16 chunks
    float acc[8] = {0,0,0,0,0,0,0,0};

    int nk = (deg + 3) >> 2;             // edge e = b + k*4 + grp
    int k = 0;
    for (; k + 4 <= nk; k += 4) {        // 16 edge-rows in flight
        int2 p[4];
        #pragma unroll
        for (int j = 0; j < 4; ++j) {
            int idx = b + (k + j) * 4 + grp;
            int idc = (idx < en) ? idx : b;
            p[j] = csr[idc];
            if (idx >= en) p[j].y = 0;
        }
        f16x8 v[4];
        #pragma unroll
        for (int j = 0; j < 4; ++j)
            v[j] = av[(size_t)p[j].x * 16 + l];
        #pragma unroll
        for (int j = 0; j < 4; ++j) {
            float w = __int_as_float(p[j].y);
            #pragma unroll
            for (int i = 0; i < 8; ++i) acc[i] += w * (float)v[j][i];
        }
    }
    for (; k < nk; ++k) {
        int idx = b + k * 4 + grp;
        int idc = (idx < en) ? idx : b;
        int2 p = csr[idc];
        if (idx >= en) p.y = 0;
        f16x8 v = av[(size_t)p.x * 16 + l];
        float w = __int_as_float(p.y);
        #pragma unroll
        for (int i = 0; i < 8; ++i) acc[i] += w * (float)v[i];
    }

    #pragma unroll
    for (int i = 0; i < 8; ++i) {
        acc[i] += __shfl_xor(acc[i], 16, 64);
        acc[i] += __shfl_xor(acc[i], 32, 64);
    }

    f16x8 dv = ((const f16x8*)d)[(size_t)node * 16 + l];
    float v[8];
    float s = 0.f, ss = 0.f;
    #pragma unroll
    for (int i = 0; i < 8; ++i) {
        v[i] = acc[i] + (float)dv[i];
        s += v[i]; ss += v[i] * v[i];
    }
    #pragma unroll
    for (int off = 1; off <= 8; off <<= 1) {
        s  += __shfl_xor(s,  off, 64);
        ss += __shfl_xor(ss, off, 64);
    }
    float mean = s * (1.f / 128.f);
    float var = ss * (1.f / 128.f) - mean * mean;
    float rstd = rsqrtf(var + 1e-5f);

    const float4* gv4 = (const float4*)g;
    const float4* bv4 = (const float4*)beta;
    float4 ga = gv4[l*2], gb = gv4[l*2+1];
    float4 ba = bv4[l*2], bb = bv4[l*2+1];
    float go[8] = {ga.x,ga.y,ga.z,ga.w,gb.x,gb.y,gb.z,gb.w};
    float bo[8] = {ba.x,ba.y,ba.z,ba.w,bb.x,bb.y,bb.z,bb.w};
    f16x8 ov;
    #pragma unroll
    for (int i = 0; i < 8; ++i) {
        float o = (v[i] - mean) * rstd * go[i] + bo[i];
        o = o >= 0.f ? o : 0.1f * o;
        ov[i] = (_Float16)o;
    }
    if (grp == 0)
        ((f16x8*)out)[(size_t)node * 16 + l] = ov;
}

// ===================== output layer (D_OUT=1) =====================

__global__ __launch_bounds__(256) void out_gemv_kernel(
    const _Float16* __restrict__ h, int N,
    const float* __restrict__ W1, const float* __restrict__ b1,
    const float* __restrict__ W2,
    const float* __restrict__ W3, const float* __restrict__ b3,
    const float* __restrict__ wsum,
    float* __restrict__ a1, float* __restrict__ dpart)
{
    int wave = threadIdx.x >> 6;
    int lane = threadIdx.x & 63;
    int node = blockIdx.x * 4 + wave;
    if (node >= N) return;
    const _Float16* row = h + (size_t)node * 128;
    float h0 = (float)row[lane], h1 = (float)row[lane + 64];
    float s1 = wave_reduce_sum(h0 * W1[lane] + h1 * W1[lane + 64]);
    float s2 = wave_reduce_sum(h0 * W2[lane] + h1 * W2[lane + 64]);
    float s3 = wave_reduce_sum(h0 * W3[lane] + h1 * W3[lane + 64]);
    if (lane == 0) {
        a1[node] = s1 + b1[0];
        dpart[node] = s3 + b3[0] - wsum[node] * s2;
    }
}

__global__ __launch_bounds__(256) void gather_out_kernel(
    const int* __restrict__ rowptr, const int2* __restrict__ csr,
    const float* __restrict__ a1, const float* __restrict__ dpart,
    float* __restrict__ out, int N)
{
    int n = blockIdx.x * 256 + threadIdx.x;
    if (n >= N) return;
    int b = rowptr[n], en = rowptr[n + 1];
    float s = dpart[n];
    int e = b;
    for (; e + 4 <= en; e += 4) {
        int2 p0 = csr[e], p1 = csr[e+1], p2 = csr[e+2], p3 = csr[e+3];
        float x0 = a1[p0.x], x1 = a1[p1.x], x2 = a1[p2.x], x3 = a1[p3.x];
        s += __int_as_float(p0.y) * x0 + __int_as_float(p1.y) * x1
           + __int_as_float(p2.y) * x2 + __int_as_float(p3.y) * x3;
    }
    for (; e < en; ++e) {
        int2 p = csr[e];
        s += __int_as_float(p.y) * a1[p.x];
    }
    out[n] = 1.f / (1.f + expf(-s));
}

// ---------------------------------------------------------------------------
extern "C" void kernel_launch(void* const* d_in, const int* in_sizes, int n_in,
                              void* d_out, int out_size, void* d_ws, size_t ws_size,
                              hipStream_t stream)
{
    const float* x     = (const float*)d_in[0];
    const float* ew    = (const float*)d_in[1];
    const float* W1_in = (const float*)d_in[2];
    const float* b1_in = (const float*)d_in[3];
    const float* W2_in = (const float*)d_in[4];
    const float* W3_in = (const float*)d_in[5];
    const float* b3_in = (const float*)d_in[6];
    const float* W1_h  = (const float*)d_in[7];
    const float* b1_h  = (const float*)d_in[8];
    const float* W2_h  = (const float*)d_in[9];
    const float* W3_h  = (const float*)d_in[10];
    const float* b3_h  = (const float*)d_in[11];
    const float* W1_o  = (const float*)d_in[12];
    const float* b1_o  = (const float*)d_in[13];
    const float* W2_o  = (const float*)d_in[14];
    const float* W3_o  = (const float*)d_in[15];
    const float* b3_o  = (const float*)d_in[16];
    const float* g1    = (const float*)d_in[17];
    const float* beta1 = (const float*)d_in[18];
    const float* g2    = (const float*)d_in[19];
    const float* beta2 = (const float*)d_in[20];
    const int*   eidx  = (const int*)d_in[21];

    const int N = in_sizes[0] / 128;
    const int E = in_sizes[1];
    const int* srcp = eidx;
    const int* dstp = eidx + E;

    // ---- workspace carve-out (256B-aligned chunks) ----
    size_t off = 0;
    auto carve = [&](size_t nbytes) -> void* {
        void* p = (char*)d_ws + off;
        off += (nbytes + 255) & ~(size_t)255;
        return p;
    };
    int*      deg    = (int*)     carve((size_t)N * 4);
    size_t zeroBytes = off;                       // only deg needs zeroing
    int*      rank   = (int*)     carve((size_t)E * 4);
    _Float16* buf_h  = (_Float16*)carve((size_t)N * 128 * 2);
    _Float16* buf_a  = (_Float16*)carve((size_t)N * 128 * 2);
    _Float16* buf_d  = (_Float16*)carve((size_t)N * 128 * 2);
    int2*     csr    = (int2*)    carve((size_t)E * 8);
    _Float16* Wt_in  = (_Float16*)carve(384 * 128 * 2);
    _Float16* Wt_h   = (_Float16*)carve(384 * 128 * 2);
    int*      rowptr = (int*)     carve((size_t)(N + 1) * 4);
    int*      partial= (int*)     carve(256 * 4);
    float*    ps     = (float*)   carve((size_t)CS_BLOCKS * 128 * 4);
    float*    pss    = (float*)   carve((size_t)CS_BLOCKS * 128 * 4);
    float*    meanp  = (float*)   carve(128 * 4);
    float*    rstdp  = (float*)   carve(128 * 4);
    float*    wsum   = (float*)   carve((size_t)N * 4);
    float*    a1     = (float*)   carve((size_t)N * 4);
    float*    dpart  = (float*)   carve((size_t)N * 4);

    const int nodeWaveBlocks = (N + 3) / 4;
    const int eBlocks = (E + 255) / 256;
    const int nBlocks = (N + 255) / 256;
    const int nb = (N + 1023) / 1024;
    const int wBlocks = (2 * 384 * 128 + 255) / 256;

    hipMemsetAsync(deg, 0, zeroBytes, stream);

    // ---- CSR build (rank-based, no fill atomics) + weight conversion ----
    hist_kernel<<<eBlocks, 256, 0, stream>>>(dstp, deg, rank, E);
    scan_pass1<<<nb, 256, 0, stream>>>(deg, N, partial);
    scan_pass2<<<1, 256, 0, stream>>>(partial, nb);
    scan_pass3<<<nb, 256, 0, stream>>>(deg, N, partial, rowptr, E);
    csr_fill_kernel<<<eBlocks, 256, 0, stream>>>(srcp, dstp, ew, rowptr, rank, csr, E);
    wsum_csr_kernel<<<nBlocks, 256, 0, stream>>>(rowptr, csr, wsum, N);
    convert_weights_kernel<<<wBlocks, 256, 0, stream>>>(
        W1_in, W2_in, W3_in, Wt_in, W1_h, W2_h, W3_h, Wt_h);

    // ---- input standardization stats ----
    colstats_kernel<<<CS_BLOCKS, 256, 0, stream>>>(x, N, ps, pss);
    reduce_stats_kernel<<<1, 256, 0, stream>>>(ps, pss, N, meanp, rstdp);

    const int nTiles = (N + 63) / 64;
    const int gemmGrid = (nTiles < 512) ? nTiles : 512;

    // ---- layer 1 (standardize fused into GEMM staging) ----
    gemm_mfma_std_kernel<<<gemmGrid, 256, 0, stream>>>(
        x, meanp, rstdp, N, nTiles, Wt_in, b1_in, b3_in, wsum, buf_a, buf_d);
    aggregate_ln_kernel<<<nodeWaveBlocks, 256, 0, stream>>>(rowptr, csr, buf_a, buf_d, g1, beta1, buf_h, N);

    // ---- layers 2..3 ----
    for (int l = 0; l < 2; ++l) {
        gemm_mfma_kernel<<<gemmGrid, 256, 0, stream>>>(buf_h, N, nTiles, Wt_h, b1_h, b3_h, wsum, buf_a, buf_d);
        aggregate_ln_kernel<<<nodeWaveBlocks, 256, 0, stream>>>(rowptr, csr, buf_a, buf_d, g2, beta2, buf_h, N);
    }

    // ---- output layer ----
    out_gemv_kernel<<<nodeWaveBlocks, 256, 0, stream>>>(buf_h, N, W1_o, b1_o, W2_o, W3_o, b3_o, wsum, a1, dpart);
    gather_out_kernel<<<nBlocks, 256, 0, stream>>>(rowptr, csr, a1, dpart, (float*)d_out, N);
}

// Round 13
// 328.845 us; speedup vs baseline: 1.2855x; 1.0270x over previous
//
#include <hip/hip_runtime.h>
#include <hip/hip_bf16.h>
#include <math.h>

// ---------------------------------------------------------------------------
// GNN_72103910966081: 4-layer LEConv GNN, N=50000, E=600000, D=128.
// Round 13: fuse output-layer GEMV into the final aggregate (aggregate_out):
// the post-LN row lives in registers — 3 dot products via 16-lane reduce,
// deleting out_gemv's dispatch + buf_h round-trip (12.8MB w + 12.8MB r).
// ---------------------------------------------------------------------------

typedef _Float16 f16x8 __attribute__((ext_vector_type(8)));
typedef _Float16 f16x4 __attribute__((ext_vector_type(4)));
typedef float f32x4 __attribute__((ext_vector_type(4)));

#define LSTRIDE 136   // halves per LDS row: 128 + 8 (16B-aligned, breaks 2^k banks)

__device__ inline float wave_reduce_sum(float v) {
    #pragma unroll
    for (int off = 32; off > 0; off >>= 1)
        v += __shfl_xor(v, off, 64);
    return v;
}

// ===================== CSR build =====================

// histogram + per-edge within-row rank (atomicAdd return value)
__global__ __launch_bounds__(256) void hist_kernel(
    const int* __restrict__ dst, int* __restrict__ deg,
    int* __restrict__ rank, int E)
{
    int e = blockIdx.x * 256 + threadIdx.x;
    if (e < E) rank[e] = atomicAdd(&deg[dst[e]], 1);
}

__global__ __launch_bounds__(256) void scan_pass1(
    const int* __restrict__ deg, int N, int* __restrict__ partial)
{
    __shared__ int sh[256];
    int t = threadIdx.x;
    int base = blockIdx.x * 1024 + t * 4;
    int s = 0;
    #pragma unroll
    for (int i = 0; i < 4; ++i) { int idx = base + i; if (idx < N) s += deg[idx]; }
    sh[t] = s; __syncthreads();
    for (int off = 128; off > 0; off >>= 1) {
        if (t < off) sh[t] += sh[t + off];
        __syncthreads();
    }
    if (t == 0) partial[blockIdx.x] = sh[0];
}

__global__ __launch_bounds__(256) void scan_pass2(int* __restrict__ partial, int nb)
{
    __shared__ int sh[256];
    int t = threadIdx.x;
    sh[t] = (t < nb) ? partial[t] : 0;
    __syncthreads();
    for (int off = 1; off < 256; off <<= 1) {
        int x = sh[t];
        if (t >= off) x += sh[t - off];
        __syncthreads();
        sh[t] = x;
        __syncthreads();
    }
    if (t < nb) partial[t] = (t > 0) ? sh[t - 1] : 0;   // exclusive
}

__global__ __launch_bounds__(256) void scan_pass3(
    const int* __restrict__ deg, int N, const int* __restrict__ partial,
    int* __restrict__ rowptr, int E)
{
    __shared__ int sh[256];
    int t = threadIdx.x;
    int base = blockIdx.x * 1024 + t * 4;
    int v[4]; int s = 0;
    #pragma unroll
    for (int i = 0; i < 4; ++i) { int idx = base + i; v[i] = (idx < N) ? deg[idx] : 0; s += v[i]; }
    sh[t] = s; __syncthreads();
    for (int off = 1; off < 256; off <<= 1) {
        int x = sh[t];
        if (t >= off) x += sh[t - off];
        __syncthreads();
        sh[t] = x;
        __syncthreads();
    }
    int off0 = partial[blockIdx.x] + ((t > 0) ? sh[t - 1] : 0);
    #pragma unroll
    for (int i = 0; i < 4; ++i) {
        int idx = base + i;
        if (idx < N) { rowptr[idx] = off0; off0 += v[i]; }
    }
    if (blockIdx.x == 0 && t == 0) rowptr[N] = E;
}

// NO atomics: pos = rowptr[dst] + rank (rank captured in hist)
__global__ __launch_bounds__(256) void csr_fill_kernel(
    const int* __restrict__ src, const int* __restrict__ dst,
    const float* __restrict__ ew, const int* __restrict__ rowptr,
    const int* __restrict__ rank, int2* __restrict__ csr, int E)
{
    int e = blockIdx.x * 256 + threadIdx.x;
    if (e >= E) return;
    int d = dst[e];
    int pos = rowptr[d] + rank[e];
    csr[pos] = make_int2(src[e], __float_as_int(ew[e]));
}

__global__ __launch_bounds__(256) void wsum_csr_kernel(
    const int* __restrict__ rowptr, const int2* __restrict__ csr,
    float* __restrict__ wsum, int N)
{
    int n = blockIdx.x * 256 + threadIdx.x;
    if (n >= N) return;
    int b = rowptr[n], en = rowptr[n + 1];
    float s = 0.f;
    for (int e = b; e < en; ++e) s += __int_as_float(csr[e].y);
    wsum[n] = s;
}

// ===================== weight convert+transpose (both sets, one launch) ====

__global__ __launch_bounds__(256) void convert_weights_kernel(
    const float* __restrict__ W1a, const float* __restrict__ W2a,
    const float* __restrict__ W3a, _Float16* __restrict__ Wta,
    const float* __restrict__ W1b, const float* __restrict__ W2b,
    const float* __restrict__ W3b, _Float16* __restrict__ Wtb)
{
    int idx = blockIdx.x * 256 + threadIdx.x;   // over 2*384*128
    if (idx >= 2 * 384 * 128) return;
    int set = idx >= 384 * 128;
    int id = idx - set * 384 * 128;
    int n = id >> 7, k = id & 127;
    const float* W = set ? ((n < 128) ? W1b : (n < 256) ? W2b : W3b)
                         : ((n < 128) ? W1a : (n < 256) ? W2a : W3a);
    _Float16* Wt = set ? Wtb : Wta;
    int c = n & 127;
    Wt[id] = (_Float16)W[k * 128 + c];
}

// ===================== input standardization (partials, 4-deep ILP) ========

#define CS_BLOCKS 512

__global__ __launch_bounds__(256) void colstats_kernel(
    const float* __restrict__ x, int N,
    float* __restrict__ ps, float* __restrict__ pss)   // [CS_BLOCKS][128] each
{
    __shared__ float shs[256][4];
    __shared__ float shq[256][4];
    int t = threadIdx.x;
    int g = t >> 5;
    int c = t & 31;
    const float4* xv = (const float4*)x;    // row stride 32
    const int S = CS_BLOCKS * 8;            // 4096 rows
    float s0=0.f,s1=0.f,s2=0.f,s3=0.f, q0=0.f,q1=0.f,q2=0.f,q3=0.f;
    int r = blockIdx.x * 8 + g;
    for (; r + 3*S < N; r += 4*S) {
        float4 v0 = xv[(size_t)r * 32 + c];
        float4 v1 = xv[(size_t)(r + S) * 32 + c];
        float4 v2 = xv[(size_t)(r + 2*S) * 32 + c];
        float4 v3 = xv[(size_t)(r + 3*S) * 32 + c];
        s0 += v0.x + v1.x + v2.x + v3.x;
        s1 += v0.y + v1.y + v2.y + v3.y;
        s2 += v0.z + v1.z + v2.z + v3.z;
        s3 += v0.w + v1.w + v2.w + v3.w;
        q0 += v0.x*v0.x + v1.x*v1.x + v2.x*v2.x + v3.x*v3.x;
        q1 += v0.y*v0.y + v1.y*v1.y + v2.y*v2.y + v3.y*v3.y;
        q2 += v0.z*v0.z + v1.z*v1.z + v2.z*v2.z + v3.z*v3.z;
        q3 += v0.w*v0.w + v1.w*v1.w + v2.w*v2.w + v3.w*v3.w;
    }
    for (; r < N; r += S) {
        float4 v = xv[(size_t)r * 32 + c];
        s0 += v.x; s1 += v.y; s2 += v.z; s3 += v.w;
        q0 += v.x*v.x; q1 += v.y*v.y; q2 += v.z*v.z; q3 += v.w*v.w;
    }
    shs[t][0]=s0; shs[t][1]=s1; shs[t][2]=s2; shs[t][3]=s3;
    shq[t][0]=q0; shq[t][1]=q1; shq[t][2]=q2; shq[t][3]=q3;
    __syncthreads();
    if (t < 32) {
        float S4[4] = {0,0,0,0}, Q4[4] = {0,0,0,0};
        #pragma unroll
        for (int gg = 0; gg < 8; ++gg) {
            #pragma unroll
            for (int i = 0; i < 4; ++i) {
                S4[i] += shs[t + 32*gg][i];
                Q4[i] += shq[t + 32*gg][i];
            }
        }
        #pragma unroll
        for (int i = 0; i < 4; ++i) {
            ps [blockIdx.x * 128 + t*4 + i] = S4[i];
            pss[blockIdx.x * 128 + t*4 + i] = Q4[i];
        }
    }
}

__global__ __launch_bounds__(256) void reduce_stats_kernel(
    const float* __restrict__ ps, const float* __restrict__ pss, int N,
    float* __restrict__ mean, float* __restrict__ rstd)
{
    __shared__ float sh[256];
    int t = threadIdx.x;           // 256
    int f = t & 127;
    const float* src = (t >= 128) ? pss : ps;
    float s = 0.f;
    int r = 0;
    for (; r + 4 <= CS_BLOCKS; r += 4) {
        float a0 = src[(r    ) * 128 + f];
        float a1 = src[(r + 1) * 128 + f];
        float a2 = src[(r + 2) * 128 + f];
        float a3 = src[(r + 3) * 128 + f];
        s += (a0 + a1) + (a2 + a3);
    }
    for (; r < CS_BLOCKS; ++r) s += src[r * 128 + f];
    sh[t] = s;
    __syncthreads();
    if (t < 128) {
        float sum = sh[t], sumsq = sh[t + 128];
        float m = sum / (float)N;
        float var = (sumsq - sum * sum / (float)N) / (float)(N - 1);  // ddof=1
        var = fmaxf(var, 0.f);
        mean[t] = m;
        rstd[t] = 1.f / (sqrtf(var) + 1e-6f);
    }
}

// ===================== MFMA fused GEMM (persistent, B in registers) ========
// Variant 1: reads fp16 h (layers 2..3).

__global__ __launch_bounds__(256, 2) void gemm_mfma_kernel(
    const _Float16* __restrict__ h, int N, int nTiles,
    const _Float16* __restrict__ Wt,
    const float* __restrict__ b1,
    const float* __restrict__ b3,
    const float* __restrict__ wsum,
    _Float16* __restrict__ out_a, _Float16* __restrict__ out_d)
{
    __shared__ _Float16 ldsS[64 * LSTRIDE];
    __shared__ _Float16 lds_a[64 * LSTRIDE];
    __shared__ _Float16 lds_d[64 * LSTRIDE];

    int t = threadIdx.x;
    int wave = t >> 6;
    int lane = t & 63;
    int quad = lane >> 4;
    int c16  = lane & 15;

    const f16x8* wv = (const f16x8*)Wt;
    int ntl[6] = {2*wave, 2*wave+1, 8+2*wave, 9+2*wave, 16+2*wave, 17+2*wave};
    f16x8 bfrag[6][4];
    #pragma unroll
    for (int j = 0; j < 6; ++j) {
        int nrow = ntl[j] * 16 + c16;
        #pragma unroll
        for (int s = 0; s < 4; ++s)
            bfrag[j][s] = wv[(size_t)nrow * 16 + s * 4 + quad];
    }
    float bb1[2], bb3[2];
    #pragma unroll
    for (int j = 0; j < 2; ++j) {
        int col = (2*wave + j) * 16 + c16;
        bb1[j] = b1[col];
        bb3[j] = b3[col];
    }

    const f16x8* hv = (const f16x8*)h;
    f16x8* oa = (f16x8*)out_a;
    f16x8* od = (f16x8*)out_d;

    for (int tile = blockIdx.x; tile < nTiles; tile += gridDim.x) {
        int row0 = tile * 64;

        #pragma unroll
        for (int i = 0; i < 4; ++i) {
            int idx = i * 256 + t;
            int row = idx >> 4;
            int chunk = idx & 15;
            int grow = row0 + row;
            if (grow >= N) grow = N - 1;
            *(f16x8*)&ldsS[row * LSTRIDE + chunk * 8] = hv[(size_t)grow * 16 + chunk];
        }
        __syncthreads();

        #pragma unroll
        for (int r = 0; r < 4; ++r) {
            f16x8 afrag[4];
            #pragma unroll
            for (int s = 0; s < 4; ++s)
                afrag[s] = *(const f16x8*)&ldsS[(r*16 + c16) * LSTRIDE + (s*4 + quad) * 8];

            f32x4 acc[6];
            #pragma unroll
            for (int j = 0; j < 6; ++j) acc[j] = (f32x4){0.f, 0.f, 0.f, 0.f};
            #pragma unroll
            for (int s = 0; s < 4; ++s) {
                #pragma unroll
                for (int j = 0; j < 6; ++j)
                    acc[j] = __builtin_amdgcn_mfma_f32_16x16x32_f16(afrag[s], bfrag[j][s], acc[j], 0, 0, 0);
            }

            float wsv[4];
            #pragma unroll
            for (int reg = 0; reg < 4; ++reg) {
                int gr = row0 + r*16 + quad*4 + reg;
                wsv[reg] = wsum[(gr < N) ? gr : (N - 1)];
            }
            #pragma unroll
            for (int j = 0; j < 2; ++j) {
                int col = (2*wave + j) * 16 + c16;
                #pragma unroll
                for (int reg = 0; reg < 4; ++reg) {
                    int lr = r*16 + quad*4 + reg;
                    lds_a[lr * LSTRIDE + col] = (_Float16)(acc[j][reg] + bb1[j]);
                    lds_d[lr * LSTRIDE + col] =
                        (_Float16)(acc[4+j][reg] + bb3[j] - wsv[reg] * acc[2+j][reg]);
                }
            }
        }
        __syncthreads();

        #pragma unroll
        for (int i = 0; i < 4; ++i) {
            int idx = i * 256 + t;
            int row = idx >> 4;
            int c8  = idx & 15;
            int grow = row0 + row;
            if (grow < N) {
                f16x8 va = *(const f16x8*)&lds_a[row * LSTRIDE + c8 * 8];
                oa[(size_t)grow * 16 + c8] = va;
                f16x8 vd = *(const f16x8*)&lds_d[row * LSTRIDE + c8 * 8];
                od[(size_t)grow * 16 + c8] = vd;
            }
        }
        __syncthreads();
    }
}

// Variant 2 (layer 1): reads fp32 x, fuses standardization into staging.

__global__ __launch_bounds__(256, 2) void gemm_mfma_std_kernel(
    const float* __restrict__ x,
    const float* __restrict__ meanp, const float* __restrict__ rstdp,
    int N, int nTiles,
    const _Float16* __restrict__ Wt,
    const float* __restrict__ b1,
    const float* __restrict__ b3,
    const float* __restrict__ wsum,
    _Float16* __restrict__ out_a, _Float16* __restrict__ out_d)
{
    __shared__ _Float16 ldsS[64 * LSTRIDE];
    __shared__ _Float16 lds_a[64 * LSTRIDE];
    __shared__ _Float16 lds_d[64 * LSTRIDE];

    int t = threadIdx.x;
    int wave = t >> 6;
    int lane = t & 63;
    int quad = lane >> 4;
    int c16  = lane & 15;

    const f16x8* wv = (const f16x8*)Wt;
    int ntl[6] = {2*wave, 2*wave+1, 8+2*wave, 9+2*wave, 16+2*wave, 17+2*wave};
    f16x8 bfrag[6][4];
    #pragma unroll
    for (int j = 0; j < 6; ++j) {
        int nrow = ntl[j] * 16 + c16;
        #pragma unroll
        for (int s = 0; s < 4; ++s)
            bfrag[j][s] = wv[(size_t)nrow * 16 + s * 4 + quad];
    }
    float bb1[2], bb3[2];
    #pragma unroll
    for (int j = 0; j < 2; ++j) {
        int col = (2*wave + j) * 16 + c16;
        bb1[j] = b1[col];
        bb3[j] = b3[col];
    }

    int c4 = t & 31;
    float4 mu = ((const float4*)meanp)[c4];
    float4 rs = ((const float4*)rstdp)[c4];

    const float4* xv = (const float4*)x;   // row stride 32 float4
    f16x8* oa = (f16x8*)out_a;
    f16x8* od = (f16x8*)out_d;

    for (int tile = blockIdx.x; tile < nTiles; tile += gridDim.x) {
        int row0 = tile * 64;

        #pragma unroll
        for (int i = 0; i < 8; ++i) {
            int idx = i * 256 + t;        // 0..2047
            int row = idx >> 5;           // 0..63
            int grow = row0 + row;
            if (grow >= N) grow = N - 1;
            float4 v = xv[(size_t)grow * 32 + c4];
            f16x4 o;
            o.x = (_Float16)((v.x - mu.x) * rs.x);
            o.y = (_Float16)((v.y - mu.y) * rs.y);
            o.z = (_Float16)((v.z - mu.z) * rs.z);
            o.w = (_Float16)((v.w - mu.w) * rs.w);
            *(f16x4*)&ldsS[row * LSTRIDE + c4 * 4] = o;
        }
        __syncthreads();

        #pragma unroll
        for (int r = 0; r < 4; ++r) {
            f16x8 afrag[4];
            #pragma unroll
            for (int s = 0; s < 4; ++s)
                afrag[s] = *(const f16x8*)&ldsS[(r*16 + c16) * LSTRIDE + (s*4 + quad) * 8];

            f32x4 acc[6];
            #pragma unroll
            for (int j = 0; j < 6; ++j) acc[j] = (f32x4){0.f, 0.f, 0.f, 0.f};
            #pragma unroll
            for (int s = 0; s < 4; ++s) {
                #pragma unroll
                for (int j = 0; j < 6; ++j)
                    acc[j] = __builtin_amdgcn_mfma_f32_16x16x32_f16(afrag[s], bfrag[j][s], acc[j], 0, 0, 0);
            }

            float wsv[4];
            #pragma unroll
            for (int reg = 0; reg < 4; ++reg) {
                int gr = row0 + r*16 + quad*4 + reg;
                wsv[reg] = wsum[(gr < N) ? gr : (N - 1)];
            }
            #pragma unroll
            for (int j = 0; j < 2; ++j) {
                int col = (2*wave + j) * 16 + c16;
                #pragma unroll
                for (int reg = 0; reg < 4; ++reg) {
                    int lr = r*16 + quad*4 + reg;
                    lds_a[lr * LSTRIDE + col] = (_Float16)(acc[j][reg] + bb1[j]);
                    lds_d[lr * LSTRIDE + col] =
                        (_Float16)(acc[4+j][reg] + bb3[j] - wsv[reg] * acc[2+j][reg]);
                }
            }
        }
        __syncthreads();

        #pragma unroll
        for (int i = 0; i < 4; ++i) {
            int idx = i * 256 + t;
            int row = idx >> 4;
            int c8  = idx & 15;
            int grow = row0 + row;
            if (grow < N) {
                f16x8 va = *(const f16x8*)&lds_a[row * LSTRIDE + c8 * 8];
                oa[(size_t)grow * 16 + c8] = va;
                f16x8 vd = *(const f16x8*)&lds_d[row * LSTRIDE + c8 * 8];
                od[(size_t)grow * 16 + c8] = vd;
            }
        }
        __syncthreads();
    }
}

// ===================== fused gather + LN + leaky (mid layers) ==============
// 1 node per wave; 4 edge-groups x 16 lanes x f16x8 (16B/lane).

__global__ __launch_bounds__(256) void aggregate_ln_kernel(
    const int* __restrict__ rowptr, const int2* __restrict__ csr,
    const _Float16* __restrict__ a, const _Float16* __restrict__ d,
    const float* __restrict__ g, const float* __restrict__ beta,
    _Float16* __restrict__ out, int N)
{
    int wave = threadIdx.x >> 6;
    int lane = threadIdx.x & 63;
    int grp  = lane >> 4;        // 0..3: edge group
    int l    = lane & 15;        // feature chunk: cols 8l..8l+7
    int node = blockIdx.x * 4 + wave;
    if (node >= N) return;
    int b = rowptr[node], en = rowptr[node + 1];
    int deg = en - b;

    const f16x8* av = (const f16x8*)a;   // row stride 16 chunks
    float acc[8] = {0,0,0,0,0,0,0,0};

    int nk = (deg + 3) >> 2;             // edge e = b + k*4 + grp
    int k = 0;
    for (; k + 4 <= nk; k += 4) {        // 16 edge-rows in flight
        int2 p[4];
        #pragma unroll
        for (int j = 0; j < 4; ++j) {
            int idx = b + (k + j) * 4 + grp;
            int idc = (idx < en) ? idx : b;
            p[j] = csr[idc];
            if (idx >= en) p[j].y = 0;
        }
        f16x8 v[4];
        #pragma unroll
        for (int j = 0; j < 4; ++j)
            v[j] = av[(size_t)p[j].x * 16 + l];
        #pragma unroll
        for (int j = 0; j < 4; ++j) {
            float w = __int_as_float(p[j].y);
            #pragma unroll
            for (int i = 0; i < 8; ++i) acc[i] += w * (float)v[j][i];
        }
    }
    for (; k < nk; ++k) {
        int idx = b + k * 4 + grp;
        int idc = (idx < en) ? idx : b;
        int2 p = csr[idc];
        if (idx >= en) p.y = 0;
        f16x8 v = av[(size_t)p.x * 16 + l];
        float w = __int_as_float(p.y);
        #pragma unroll
        for (int i = 0; i < 8; ++i) acc[i] += w * (float)v[i];
    }

    #pragma unroll
    for (int i = 0; i < 8; ++i) {
        acc[i] += __shfl_xor(acc[i], 16, 64);
        acc[i] += __shfl_xor(acc[i], 32, 64);
    }

    f16x8 dv = ((const f16x8*)d)[(size_t)node * 16 + l];
    float v[8];
    float s = 0.f, ss = 0.f;
    #pragma unroll
    for (int i = 0; i < 8; ++i) {
        v[i] = acc[i] + (float)dv[i];
        s += v[i]; ss += v[i] * v[i];
    }
    #pragma unroll
    for (int off = 1; off <= 8; off <<= 1) {
        s  += __shfl_xor(s,  off, 64);
        ss += __shfl_xor(ss, off, 64);
    }
    float mean = s * (1.f / 128.f);
    float var = ss * (1.f / 128.f) - mean * mean;
    float rstd = rsqrtf(var + 1e-5f);

    const float4* gv4 = (const float4*)g;
    const float4* bv4 = (const float4*)beta;
    float4 ga = gv4[l*2], gb = gv4[l*2+1];
    float4 ba = bv4[l*2], bb = bv4[l*2+1];
    float go[8] = {ga.x,ga.y,ga.z,ga.w,gb.x,gb.y,gb.z,gb.w};
    float bo[8] = {ba.x,ba.y,ba.z,ba.w,bb.x,bb.y,bb.z,bb.w};
    f16x8 ov;
    #pragma unroll
    for (int i = 0; i < 8; ++i) {
        float o = (v[i] - mean) * rstd * go[i] + bo[i];
        o = o >= 0.f ? o : 0.1f * o;
        ov[i] = (_Float16)o;
    }
    if (grp == 0)
        ((f16x8*)out)[(size_t)node * 16 + l] = ov;
}

// ===================== final aggregate + LN + leaky + output GEMV ==========
// Same as aggregate_ln but instead of writing h, computes the output layer's
// three dot products (h@W1_o, h@W2_o, h@W3_o) in-register -> a1, dpart.

__global__ __launch_bounds__(256) void aggregate_out_kernel(
    const int* __restrict__ rowptr, const int2* __restrict__ csr,
    const _Float16* __restrict__ a, const _Float16* __restrict__ d,
    const float* __restrict__ g, const float* __restrict__ beta,
    const float* __restrict__ W1o, const float* __restrict__ b1o,
    const float* __restrict__ W2o,
    const float* __restrict__ W3o, const float* __restrict__ b3o,
    const float* __restrict__ wsum,
    float* __restrict__ a1, float* __restrict__ dpart, int N)
{
    int wave = threadIdx.x >> 6;
    int lane = threadIdx.x & 63;
    int grp  = lane >> 4;
    int l    = lane & 15;
    int node = blockIdx.x * 4 + wave;
    if (node >= N) return;
    int b = rowptr[node], en = rowptr[node + 1];
    int deg = en - b;

    const f16x8* av = (const f16x8*)a;
    float acc[8] = {0,0,0,0,0,0,0,0};

    int nk = (deg + 3) >> 2;
    int k = 0;
    for (; k + 4 <= nk; k += 4) {
        int2 p[4];
        #pragma unroll
        for (int j = 0; j < 4; ++j) {
            int idx = b + (k + j) * 4 + grp;
            int idc = (idx < en) ? idx : b;
            p[j] = csr[idc];
            if (idx >= en) p[j].y = 0;
        }
        f16x8 v[4];
        #pragma unroll
        for (int j = 0; j < 4; ++j)
            v[j] = av[(size_t)p[j].x * 16 + l];
        #pragma unroll
        for (int j = 0; j < 4; ++j) {
            float w = __int_as_float(p[j].y);
            #pragma unroll
            for (int i = 0; i < 8; ++i) acc[i] += w * (float)v[j][i];
        }
    }
    for (; k < nk; ++k) {
        int idx = b + k * 4 + grp;
        int idc = (idx < en) ? idx : b;
        int2 p = csr[idc];
        if (idx >= en) p.y = 0;
        f16x8 v = av[(size_t)p.x * 16 + l];
        float w = __int_as_float(p.y);
        #pragma unroll
        for (int i = 0; i < 8; ++i) acc[i] += w * (float)v[i];
    }

    #pragma unroll
    for (int i = 0; i < 8; ++i) {
        acc[i] += __shfl_xor(acc[i], 16, 64);
        acc[i] += __shfl_xor(acc[i], 32, 64);
    }

    f16x8 dv = ((const f16x8*)d)[(size_t)node * 16 + l];
    float v[8];
    float s = 0.f, ss = 0.f;
    #pragma unroll
    for (int i = 0; i < 8; ++i) {
        v[i] = acc[i] + (float)dv[i];
        s += v[i]; ss += v[i] * v[i];
    }
    #pragma unroll
    for (int off = 1; off <= 8; off <<= 1) {
        s  += __shfl_xor(s,  off, 64);
        ss += __shfl_xor(ss, off, 64);
    }
    float mean = s * (1.f / 128.f);
    float var = ss * (1.f / 128.f) - mean * mean;
    float rstd = rsqrtf(var + 1e-5f);

    const float4* gv4 = (const float4*)g;
    const float4* bv4 = (const float4*)beta;
    float4 ga = gv4[l*2], gb = gv4[l*2+1];
    float4 ba = bv4[l*2], bb = bv4[l*2+1];
    float go[8] = {ga.x,ga.y,ga.z,ga.w,gb.x,gb.y,gb.z,gb.w};
    float bo[8] = {ba.x,ba.y,ba.z,ba.w,bb.x,bb.y,bb.z,bb.w};

    // post-LN/leaky row element; round-trip through f16 to match the
    // two-kernel path bit-for-bit (out_gemv used to read f16 h).
    float ho[8];
    #pragma unroll
    for (int i = 0; i < 8; ++i) {
        float o = (v[i] - mean) * rstd * go[i] + bo[i];
        o = o >= 0.f ? o : 0.1f * o;
        ho[i] = (float)(_Float16)o;
    }

    // three dot products over the 128-row: lane l holds cols 8l..8l+7
    const float4* w1v = (const float4*)W1o;
    const float4* w2v = (const float4*)W2o;
    const float4* w3v = (const float4*)W3o;
    float4 w1a = w1v[l*2], w1b = w1v[l*2+1];
    float4 w2a = w2v[l*2], w2b = w2v[l*2+1];
    float4 w3a = w3v[l*2], w3b = w3v[l*2+1];
    float s1 = ho[0]*w1a.x + ho[1]*w1a.y + ho[2]*w1a.z + ho[3]*w1a.w
             + ho[4]*w1b.x + ho[5]*w1b.y + ho[6]*w1b.z + ho[7]*w1b.w;
    float s2 = ho[0]*w2a.x + ho[1]*w2a.y + ho[2]*w2a.z + ho[3]*w2a.w
             + ho[4]*w2b.x + ho[5]*w2b.y + ho[6]*w2b.z + ho[7]*w2b.w;
    float s3 = ho[0]*w3a.x + ho[1]*w3a.y + ho[2]*w3a.z + ho[3]*w3a.w
             + ho[4]*w3b.x + ho[5]*w3b.y + ho[6]*w3b.z + ho[7]*w3b.w;
    #pragma unroll
    for (int off = 1; off <= 8; off <<= 1) {
        s1 += __shfl_xor(s1, off, 64);
        s2 += __shfl_xor(s2, off, 64);
        s3 += __shfl_xor(s3, off, 64);
    }
    if (lane == 0) {
        a1[node] = s1 + b1o[0];
        dpart[node] = s3 + b3o[0] - wsum[node] * s2;
    }
}

// ===================== output gather + sigmoid =====================

__global__ __launch_bounds__(256) void gather_out_kernel(
    const int* __restrict__ rowptr, const int2* __restrict__ csr,
    const float* __restrict__ a1, const float* __restrict__ dpart,
    float* __restrict__ out, int N)
{
    int n = blockIdx.x * 256 + threadIdx.x;
    if (n >= N) return;
    int b = rowptr[n], en = rowptr[n + 1];
    float s = dpart[n];
    int e = b;
    for (; e + 4 <= en; e += 4) {
        int2 p0 = csr[e], p1 = csr[e+1], p2 = csr[e+2], p3 = csr[e+3];
        float x0 = a1[p0.x], x1 = a1[p1.x], x2 = a1[p2.x], x3 = a1[p3.x];
        s += __int_as_float(p0.y) * x0 + __int_as_float(p1.y) * x1
           + __int_as_float(p2.y) * x2 + __int_as_float(p3.y) * x3;
    }
    for (; e < en; ++e) {
        int2 p = csr[e];
        s += __int_as_float(p.y) * a1[p.x];
    }
    out[n] = 1.f / (1.f + expf(-s));
}

// ---------------------------------------------------------------------------
extern "C" void kernel_launch(void* const* d_in, const int* in_sizes, int n_in,
                              void* d_out, int out_size, void* d_ws, size_t ws_size,
                              hipStream_t stream)
{
    const float* x     = (const float*)d_in[0];
    const float* ew    = (const float*)d_in[1];
    const float* W1_in = (const float*)d_in[2];
    const float* b1_in = (const float*)d_in[3];
    const float* W2_in = (const float*)d_in[4];
    const float* W3_in = (const float*)d_in[5];
    const float* b3_in = (const float*)d_in[6];
    const float* W1_h  = (const float*)d_in[7];
    const float* b1_h  = (const float*)d_in[8];
    const float* W2_h  = (const float*)d_in[9];
    const float* W3_h  = (const float*)d_in[10];
    const float* b3_h  = (const float*)d_in[11];
    const float* W1_o  = (const float*)d_in[12];
    const float* b1_o  = (const float*)d_in[13];
    const float* W2_o  = (const float*)d_in[14];
    const float* W3_o  = (const float*)d_in[15];
    const float* b3_o  = (const float*)d_in[16];
    const float* g1    = (const float*)d_in[17];
    const float* beta1 = (const float*)d_in[18];
    const float* g2    = (const float*)d_in[19];
    const float* beta2 = (const float*)d_in[20];
    const int*   eidx  = (const int*)d_in[21];

    const int N = in_sizes[0] / 128;
    const int E = in_sizes[1];
    const int* srcp = eidx;
    const int* dstp = eidx + E;

    // ---- workspace carve-out (256B-aligned chunks) ----
    size_t off = 0;
    auto carve = [&](size_t nbytes) -> void* {
        void* p = (char*)d_ws + off;
        off += (nbytes + 255) & ~(size_t)255;
        return p;
    };
    int*      deg    = (int*)     carve((size_t)N * 4);
    size_t zeroBytes = off;                       // only deg needs zeroing
    int*      rank   = (int*)     carve((size_t)E * 4);
    _Float16* buf_h  = (_Float16*)carve((size_t)N * 128 * 2);
    _Float16* buf_a  = (_Float16*)carve((size_t)N * 128 * 2);
    _Float16* buf_d  = (_Float16*)carve((size_t)N * 128 * 2);
    int2*     csr    = (int2*)    carve((size_t)E * 8);
    _Float16* Wt_in  = (_Float16*)carve(384 * 128 * 2);
    _Float16* Wt_h   = (_Float16*)carve(384 * 128 * 2);
    int*      rowptr = (int*)     carve((size_t)(N + 1) * 4);
    int*      partial= (int*)     carve(256 * 4);
    float*    ps     = (float*)   carve((size_t)CS_BLOCKS * 128 * 4);
    float*    pss    = (float*)   carve((size_t)CS_BLOCKS * 128 * 4);
    float*    meanp  = (float*)   carve(128 * 4);
    float*    rstdp  = (float*)   carve(128 * 4);
    float*    wsum   = (float*)   carve((size_t)N * 4);
    float*    a1     = (float*)   carve((size_t)N * 4);
    float*    dpart  = (float*)   carve((size_t)N * 4);

    const int nodeWaveBlocks = (N + 3) / 4;
    const int eBlocks = (E + 255) / 256;
    const int nBlocks = (N + 255) / 256;
    const int nb = (N + 1023) / 1024;
    const int wBlocks = (2 * 384 * 128 + 255) / 256;

    hipMemsetAsync(deg, 0, zeroBytes, stream);

    // ---- CSR build (rank-based, no fill atomics) + weight conversion ----
    hist_kernel<<<eBlocks, 256, 0, stream>>>(dstp, deg, rank, E);
    scan_pass1<<<nb, 256, 0, stream>>>(deg, N, partial);
    scan_pass2<<<1, 256, 0, stream>>>(partial, nb);
    scan_pass3<<<nb, 256, 0, stream>>>(deg, N, partial, rowptr, E);
    csr_fill_kernel<<<eBlocks, 256, 0, stream>>>(srcp, dstp, ew, rowptr, rank, csr, E);
    wsum_csr_kernel<<<nBlocks, 256, 0, stream>>>(rowptr, csr, wsum, N);
    convert_weights_kernel<<<wBlocks, 256, 0, stream>>>(
        W1_in, W2_in, W3_in, Wt_in, W1_h, W2_h, W3_h, Wt_h);

    // ---- input standardization stats ----
    colstats_kernel<<<CS_BLOCKS, 256, 0, stream>>>(x, N, ps, pss);
    reduce_stats_kernel<<<1, 256, 0, stream>>>(ps, pss, N, meanp, rstdp);

    const int nTiles = (N + 63) / 64;
    const int gemmGrid = (nTiles < 512) ? nTiles : 512;

    // ---- layer 1 (standardize fused into GEMM staging) ----
    gemm_mfma_std_kernel<<<gemmGrid, 256, 0, stream>>>(
        x, meanp, rstdp, N, nTiles, Wt_in, b1_in, b3_in, wsum, buf_a, buf_d);
    aggregate_ln_kernel<<<nodeWaveBlocks, 256, 0, stream>>>(rowptr, csr, buf_a, buf_d, g1, beta1, buf_h, N);

    // ---- layer 2 ----
    gemm_mfma_kernel<<<gemmGrid, 256, 0, stream>>>(buf_h, N, nTiles, Wt_h, b1_h, b3_h, wsum, buf_a, buf_d);
    aggregate_ln_kernel<<<nodeWaveBlocks, 256, 0, stream>>>(rowptr, csr, buf_a, buf_d, g2, beta2, buf_h, N);

    // ---- layer 3 + output GEMV fused into the final aggregate ----
    gemm_mfma_kernel<<<gemmGrid, 256, 0, stream>>>(buf_h, N, nTiles, Wt_h, b1_h, b3_h, wsum, buf_a, buf_d);
    aggregate_out_kernel<<<nodeWaveBlocks, 256, 0, stream>>>(
        rowptr, csr, buf_a, buf_d, g2, beta2,
        W1_o, b1_o, W2_o, W3_o, b3_o, wsum, a1, dpart, N);

    // ---- output gather + sigmoid ----
    gather_out_kernel<<<nBlocks, 256, 0, stream>>>(rowptr, csr, a1, dpart, (float*)d_out, N);
}